// Round 4
// baseline (574.640 us; speedup 1.0000x reference)
//
#include <hip/hip_runtime.h>
#include <cstdint>

// ---------------------------------------------------------------------------
// SimilarityGCNEncoder: B=8, N=2048, D=512, fp32.
//   sim_mfma_topk: split-bf16 MFMA cos-sim + fused top-8, now software-
//   pipelined: double-buffered global_load_lds staging, counted vmcnt(8),
//   raw s_barrier (no vmcnt(0) drain in the main loop). Scan buffer reduced
//   to a 128x32 XOR-swizzled fp32 chunk so dbuf+scan = 80KB -> 2 blocks/CU.
//   gemm_mfma: same 2-phase counted-vmcnt pipeline (vmcnt(4)).
// ---------------------------------------------------------------------------

constexpr int Bb   = 8;
constexpr int Nn   = 2048;
constexpr int Dd   = 512;
constexpr int BN   = Bb * Nn;
constexpr int KTOP = 8;
constexpr int CAP  = 56;
constexpr int NSLICE = 4;

typedef __attribute__((ext_vector_type(8))) __bf16 bf16x8;
typedef __attribute__((ext_vector_type(4))) __bf16 bf16x4;
typedef __attribute__((ext_vector_type(2))) __bf16 bf16x2;
typedef __attribute__((ext_vector_type(4))) float  f32x4;

__device__ __forceinline__ void gload16(const void* g, void* l) {
  __builtin_amdgcn_global_load_lds((const __attribute__((address_space(1))) unsigned int*)g,
                                   (__attribute__((address_space(3))) unsigned int*)l,
                                   16, 0, 0);
}
__device__ __forceinline__ void barrier_raw() {
  asm volatile("" ::: "memory");
  __builtin_amdgcn_s_barrier();
  asm volatile("" ::: "memory");
}

// ---------------------------------------------------------------- row norms
__global__ __launch_bounds__(256) void rownorm_kernel(const float* __restrict__ feats,
                                                      float* __restrict__ rinv) {
  const int row  = blockIdx.x * 4 + (threadIdx.x >> 6);
  const int lane = threadIdx.x & 63;
  const float* p = feats + (size_t)row * Dd + lane * 8;
  float4 a = *(const float4*)p;
  float4 b = *(const float4*)(p + 4);
  float s = a.x*a.x + a.y*a.y + a.z*a.z + a.w*a.w
          + b.x*b.x + b.y*b.y + b.z*b.z + b.w*b.w;
#pragma unroll
  for (int o = 32; o; o >>= 1) s += __shfl_down(s, o);
  if (lane == 0) rinv[row] = 1.0f / fmaxf(sqrtf(s), 1e-8f);
}

// ------------------------------------------------------- hi/lo split + cast
__global__ __launch_bounds__(256) void split_kernel(const float* __restrict__ feats,
                                                    const float* __restrict__ rinv,
                                                    __bf16* __restrict__ H,
                                                    __bf16* __restrict__ L,
                                                    __bf16* __restrict__ Xb) {
  const size_t base = ((size_t)blockIdx.x * 256 + threadIdx.x) * 4;
  const float s = rinv[base >> 9];
  float4 x = *(const float4*)(feats + base);
  float xs[4] = {x.x, x.y, x.z, x.w};
  bf16x4 hv, lv, xv;
#pragma unroll
  for (int j = 0; j < 4; ++j) {
    xv[j] = (__bf16)xs[j];
    const float n = xs[j] * s;
    const __bf16 h = (__bf16)n;
    hv[j] = h;
    lv[j] = (__bf16)(n - (float)h);
  }
  *(bf16x4*)(H + base) = hv;
  *(bf16x4*)(L + base) = lv;
  *(bf16x4*)(Xb + base) = xv;
}

// ------------------------------------------------- W cast + transpose (bf16)
__global__ __launch_bounds__(256) void wcast_t(const float* __restrict__ W,
                                               __bf16* __restrict__ Wt) {
  __shared__ float t[32][33];
  const int bx = blockIdx.x * 32, by = blockIdx.y * 32;
  const int lx = threadIdx.x & 31, ly = threadIdx.x >> 5;
#pragma unroll
  for (int r = 0; r < 32; r += 8)
    t[ly + r][lx] = W[(size_t)(by + ly + r) * Dd + bx + lx];
  __syncthreads();
#pragma unroll
  for (int r = 0; r < 32; r += 8)
    Wt[(size_t)(bx + ly + r) * Dd + by + lx] = (__bf16)t[lx][ly + r];
}

// ----------------------------------------------------- top-8 insert helper
__device__ __forceinline__ void ins8(float (&tv)[8], int (&ti)[8], float v, int idx) {
#pragma unroll
  for (int q = 0; q < 8; ++q) {
    bool sw = v > tv[q];
    float a = sw ? tv[q] : v;
    int   c = sw ? ti[q] : idx;
    tv[q] = sw ? v   : tv[q];
    ti[q] = sw ? idx : ti[q];
    v = a; idx = c;
  }
}

// ------------------------------------------- split-bf16 MFMA sim + top-8
// Block: 128 rows x 512 cols (4 tiles of 128), K=512 in 64 pipelined steps.
// LDS: dbuf staging 2x32KB [buf][AH|AL|BH|BL][kgrp][row][16B] + 16KB scan.
__global__ __launch_bounds__(256, 2) void sim_mfma_topk(const __bf16* __restrict__ Hg,
                                                        const __bf16* __restrict__ Lg,
                                                        float* __restrict__ pv,
                                                        int* __restrict__ pi) {
  __shared__ __align__(16) char smem[81920];
  float* Ssh = (float*)(smem + 65536);      // [128][32] fp32, XOR-swizzled

  const int tid    = threadIdx.x;
  const int lane   = tid & 63;
  const int lane15 = tid & 15;
  const int kgrp   = (tid >> 4) & 3;
  const int wv     = tid >> 6;
  const int wrow0  = wv * 32;

  const int r0    = blockIdx.x * 128;
  const int slice = blockIdx.y;
  const int bN    = blockIdx.z * Nn;

  const __bf16* HgA  = Hg + (size_t)(bN + r0) * Dd;
  const __bf16* LgA  = Lg + (size_t)(bN + r0) * Dd;
  const __bf16* HgB0 = Hg + (size_t)(bN + slice * 512) * Dd;
  const __bf16* LgB0 = Lg + (size_t)(bN + slice * 512) * Dd;

  const int srow  = tid >> 1;
  const int shalf = tid & 1;
  const int rowg  = r0 + srow;
  float t8v[8]; int t8i[8];
#pragma unroll
  for (int q = 0; q < 8; ++q) { t8v[q] = -1.0f; t8i[q] = 0; }

  // wave wv stages one region per step: 0=AH 1=AL 2=BH 3=BL
  auto stage = [&](int t, int buf) {
    const int ct = t >> 4, kb = (t & 15) << 5;
    const __bf16* wbase =
        wv == 0 ? HgA : wv == 1 ? LgA
      : (wv == 2 ? HgB0 : LgB0) + (size_t)ct * 128 * Dd;
    char* ldsb = smem + buf * 32768 + wv * 8192;
#pragma unroll
    for (int i = 0; i < 8; ++i) {
      const int kg = i >> 1, rb = (i & 1) << 6;
      gload16(wbase + (size_t)(rb + lane) * Dd + kb + kg * 8,
              ldsb + kg * 2048 + rb * 16);
    }
  };

  f32x4 acc[2][8];
  const f32x4 z = {0.f, 0.f, 0.f, 0.f};

  stage(0, 0);
  for (int t = 0; t < 64; ++t) {
    const int cur = t & 1;
    if ((t & 15) == 0) {
#pragma unroll
      for (int i = 0; i < 2; ++i)
#pragma unroll
        for (int j = 0; j < 8; ++j) acc[i][j] = z;
    }
    if (t + 1 < 64) {
      stage(t + 1, cur ^ 1);
      asm volatile("s_waitcnt vmcnt(8)" ::: "memory");   // prev 8 done; 8 in flight
    } else {
      asm volatile("s_waitcnt vmcnt(0)" ::: "memory");
    }
    barrier_raw();                           // everyone's cur-buffer complete

    const char* sb = smem + cur * 32768;
    const int a0o = kgrp * 2048 + (wrow0 + lane15) * 16;
    bf16x8 ah0 = *(const bf16x8*)(sb + a0o);
    bf16x8 ah1 = *(const bf16x8*)(sb + a0o + 256);
    bf16x8 al0 = *(const bf16x8*)(sb + 8192 + a0o);
    bf16x8 al1 = *(const bf16x8*)(sb + 8192 + a0o + 256);
#pragma unroll
    for (int cs = 0; cs < 8; ++cs) {
      const int bo = kgrp * 2048 + (cs * 16 + lane15) * 16;
      bf16x8 bh = *(const bf16x8*)(sb + 16384 + bo);
      bf16x8 bl = *(const bf16x8*)(sb + 24576 + bo);
      acc[0][cs] = __builtin_amdgcn_mfma_f32_16x16x32_bf16(ah0, bh, acc[0][cs], 0, 0, 0);
      acc[0][cs] = __builtin_amdgcn_mfma_f32_16x16x32_bf16(ah0, bl, acc[0][cs], 0, 0, 0);
      acc[0][cs] = __builtin_amdgcn_mfma_f32_16x16x32_bf16(al0, bh, acc[0][cs], 0, 0, 0);
      acc[1][cs] = __builtin_amdgcn_mfma_f32_16x16x32_bf16(ah1, bh, acc[1][cs], 0, 0, 0);
      acc[1][cs] = __builtin_amdgcn_mfma_f32_16x16x32_bf16(ah1, bl, acc[1][cs], 0, 0, 0);
      acc[1][cs] = __builtin_amdgcn_mfma_f32_16x16x32_bf16(al1, bh, acc[1][cs], 0, 0, 0);
    }
    barrier_raw();                           // all waves done reading cur buffer

    if ((t & 15) == 15) {                    // tile done -> chunked scan
      const int ct = t >> 4;
      const int ctile0 = slice * 512 + ct * 128;
#pragma unroll
      for (int ch = 0; ch < 4; ++ch) {       // static ch -> static acc indices
#pragma unroll
        for (int rs = 0; rs < 2; ++rs)
#pragma unroll
          for (int p = 0; p < 2; ++p) {
            const int cs = ch * 2 + p;
#pragma unroll
            for (int e = 0; e < 4; ++e) {
              const int row = wrow0 + rs * 16 + kgrp * 4 + e;
              const int col = p * 16 + lane15;
              Ssh[row * 32 + (col ^ ((row & 7) << 2))] = acc[rs][cs][e];
            }
          }
        barrier_raw();
        const int cbase = ctile0 + ch * 32 + shalf * 16;
        const int sw = (srow & 7) << 2;
#pragma unroll
        for (int c = 0; c < 16; ++c) {
          const float raw = Ssh[srow * 32 + ((shalf * 16 + c) ^ sw)];
          const float v = (raw + 1.0f) * 0.5f;
          const int gcol = cbase + c;
          if (gcol != rowg && v > t8v[7]) ins8(t8v, t8i, v, gcol);
        }
        barrier_raw();
      }
    }
  }

  // merge the two col-half partials per row, write slice partial
  float* Mv = Ssh;                            // [128][8]
  int*   Mi = (int*)(smem + 65536 + 4096);
  if (shalf) {
#pragma unroll
    for (int q = 0; q < 8; ++q) { Mv[srow * 8 + q] = t8v[q]; Mi[srow * 8 + q] = t8i[q]; }
  }
  barrier_raw();
  if (!shalf) {
#pragma unroll
    for (int q = 0; q < 8; ++q) {
      const float v = Mv[srow * 8 + q];
      if (v > t8v[7]) ins8(t8v, t8i, v, Mi[srow * 8 + q]);
    }
    const int prow = bN + rowg;
#pragma unroll
    for (int q = 0; q < 8; ++q) {
      pv[(prow * NSLICE + slice) * 8 + q] = t8v[q];
      pi[(prow * NSLICE + slice) * 8 + q] = bN + t8i[q];
    }
  }
}

// ----------------------------------------------------- merge slice partials
__global__ __launch_bounds__(256) void merge_topk(const float* __restrict__ pv,
                                                  const int* __restrict__ pi,
                                                  float* __restrict__ topv,
                                                  int* __restrict__ topi) {
  const int row = blockIdx.x * 256 + threadIdx.x;
  if (row >= BN) return;
  float tv[8]; int ti[8];
#pragma unroll
  for (int q = 0; q < 8; ++q) { tv[q] = -1.0f; ti[q] = 0; }
  for (int s = 0; s < NSLICE; ++s)
#pragma unroll
    for (int q = 0; q < 8; ++q) {
      const float v = pv[(row * NSLICE + s) * 8 + q];
      if (v > tv[7]) ins8(tv, ti, v, pi[(row * NSLICE + s) * 8 + q]);
    }
#pragma unroll
  for (int q = 0; q < 8; ++q) { topv[row * 8 + q] = tv[q]; topi[row * 8 + q] = ti[q]; }
}

// ------------------------------------------------------------- build edges
__global__ __launch_bounds__(256) void build_edges_kernel(const float* __restrict__ topv,
                                                          const int* __restrict__ topi,
                                                          int* __restrict__ ecnt,
                                                          int* __restrict__ eidx,
                                                          float* __restrict__ ew) {
  const int r = blockIdx.x * 256 + threadIdx.x;
  if (r >= BN) return;
#pragma unroll
  for (int t = 0; t < KTOP; ++t) {
    const float v = topv[r * KTOP + t];
    if (v > 0.0f) {
      const int j = topi[r * KTOP + t];
      const float w = 0.5f * v;
      int p = atomicAdd(&ecnt[r], 1);
      if (p < CAP) { eidx[r * CAP + p] = j; ew[r * CAP + p] = w; }
      int q = atomicAdd(&ecnt[j], 1);
      if (q < CAP) { eidx[j * CAP + q] = r; ew[j * CAP + q] = w; }
    }
  }
}

// ------------------------------------------------------------------ degree
__global__ __launch_bounds__(256) void deg_kernel(const int* __restrict__ ecnt,
                                                  const float* __restrict__ ew,
                                                  float* __restrict__ dis) {
  const int r = blockIdx.x * 256 + threadIdx.x;
  if (r >= BN) return;
  const int cnt = min(ecnt[r], CAP);
  float d = 1.0f;
  for (int e = 0; e < cnt; ++e) d += ew[r * CAP + e];
  dis[r] = rsqrtf(fmaxf(d, 1e-8f));
}

// ----------------------------------------------- y = x @ W via bf16 MFMA
// Tile 128x128, dbuf staging 2x16KB, counted vmcnt(4) pipeline.
__global__ __launch_bounds__(256, 2) void gemm_mfma(const __bf16* __restrict__ Xb,
                                                    const __bf16* __restrict__ Wt,
                                                    float* __restrict__ Y) {
  __shared__ __align__(16) char smem[32768];
  const int tid    = threadIdx.x;
  const int lane   = tid & 63;
  const int lane15 = tid & 15;
  const int kgrp   = (tid >> 4) & 3;
  const int wv     = tid >> 6;
  const int m0 = blockIdx.x * 128, n0 = blockIdx.y * 128;

  auto stage = [&](int t, int buf) {
    const int kb = t << 5;
#pragma unroll
    for (int i = 0; i < 4; ++i) {
      const int c = (wv << 2) + i;           // 0..15: 0-7 X, 8-15 Wt
      const int kg = (c & 7) >> 1, rb = (c & 1) << 6;
      const __bf16* g = (c >> 3)
          ? Wt + (size_t)(n0 + rb + lane) * Dd + kb + kg * 8
          : Xb + (size_t)(m0 + rb + lane) * Dd + kb + kg * 8;
      gload16(g, smem + buf * 16384 + ((c >> 3) << 13) + kg * 2048 + rb * 16);
    }
  };

  f32x4 acc[2][8];
  const f32x4 z = {0.f, 0.f, 0.f, 0.f};
#pragma unroll
  for (int i = 0; i < 2; ++i)
#pragma unroll
    for (int j = 0; j < 8; ++j) acc[i][j] = z;

  stage(0, 0);
  for (int t = 0; t < 16; ++t) {
    const int cur = t & 1;
    if (t + 1 < 16) {
      stage(t + 1, cur ^ 1);
      asm volatile("s_waitcnt vmcnt(4)" ::: "memory");
    } else {
      asm volatile("s_waitcnt vmcnt(0)" ::: "memory");
    }
    barrier_raw();

    const char* sb = smem + cur * 16384;
    const int a0o = kgrp * 2048 + (wv * 32 + lane15) * 16;
    bf16x8 a0 = *(const bf16x8*)(sb + a0o);
    bf16x8 a1 = *(const bf16x8*)(sb + a0o + 256);
#pragma unroll
    for (int cs = 0; cs < 8; ++cs) {
      bf16x8 b = *(const bf16x8*)(sb + 8192 + kgrp * 2048 + (cs * 16 + lane15) * 16);
      acc[0][cs] = __builtin_amdgcn_mfma_f32_16x16x32_bf16(a0, b, acc[0][cs], 0, 0, 0);
      acc[1][cs] = __builtin_amdgcn_mfma_f32_16x16x32_bf16(a1, b, acc[1][cs], 0, 0, 0);
    }
    barrier_raw();
  }
  const int rgrp = lane >> 4;
#pragma unroll
  for (int rs = 0; rs < 2; ++rs)
#pragma unroll
    for (int cs = 0; cs < 8; ++cs)
#pragma unroll
      for (int e = 0; e < 4; ++e) {
        const int row = m0 + wv * 32 + rs * 16 + rgrp * 4 + e;
        const int col = n0 + cs * 16 + lane15;
        Y[(size_t)row * Dd + col] = acc[rs][cs][e];
      }
}

// -------------------------------------------------- aggregation + LN (+LN)
__device__ inline void breduce2(float& s, float& q, float* red) {
#pragma unroll
  for (int o = 32; o; o >>= 1) { s += __shfl_down(s, o); q += __shfl_down(q, o); }
  const int wid = threadIdx.x >> 6, lane = threadIdx.x & 63;
  if (lane == 0) { red[wid * 2] = s; red[wid * 2 + 1] = q; }
  __syncthreads();
  if (threadIdx.x == 0) {
    float S = 0.f, Q = 0.f;
#pragma unroll
    for (int w2 = 0; w2 < 4; ++w2) { S += red[w2 * 2]; Q += red[w2 * 2 + 1]; }
    red[8] = S; red[9] = Q;
  }
  __syncthreads();
  s = red[8]; q = red[9];
}

template <bool FINAL>
__global__ __launch_bounds__(256) void agg_ln_kernel(const float* __restrict__ y,
                                                     const float* __restrict__ xres_f,
                                                     const __bf16* __restrict__ xres_b,
                                                     const int* __restrict__ ecnt,
                                                     const int* __restrict__ eidx,
                                                     const float* __restrict__ ew,
                                                     const float* __restrict__ dis,
                                                     const float* __restrict__ g1,
                                                     const float* __restrict__ b1v,
                                                     const float* __restrict__ g2,
                                                     const float* __restrict__ b2v,
                                                     float* __restrict__ outf,
                                                     __bf16* __restrict__ outb) {
  __shared__ float red[10];
  const int row = blockIdx.x;
  const int tid = threadIdx.x;
  const int d0 = tid * 2;
  const float di = dis[row];

  float2 yv = *(const float2*)(y + (size_t)row * Dd + d0);
  float a0 = di * di * yv.x, a1 = di * di * yv.y;
  const int cnt = min(ecnt[row], CAP);
  for (int e = 0; e < cnt; ++e) {
    const int j = eidx[row * CAP + e];
    const float c = ew[row * CAP + e] * di * dis[j];
    float2 v = *(const float2*)(y + (size_t)j * Dd + d0);
    a0 += c * v.x; a1 += c * v.y;
  }
  if (FINAL) {
    const unsigned short* xp = (const unsigned short*)xres_b + (size_t)row * Dd + d0;
    ushort2 u = *(const ushort2*)xp;
    a0 += __uint_as_float((unsigned)u.x << 16);
    a1 += __uint_as_float((unsigned)u.y << 16);
  } else {
    float2 xv = *(const float2*)(xres_f + (size_t)row * Dd + d0);
    a0 += xv.x; a1 += xv.y;
  }

  float s = a0 + a1, q = a0 * a0 + a1 * a1;
  breduce2(s, q, red);
  const float mu = s * (1.0f / Dd);
  const float var = q * (1.0f / Dd) - mu * mu;
  const float rs = rsqrtf(var + 1e-5f);
  float t0 = fmaxf((a0 - mu) * rs * g1[d0]     + b1v[d0],     0.0f);
  float t1 = fmaxf((a1 - mu) * rs * g1[d0 + 1] + b1v[d0 + 1], 0.0f);

  if (FINAL) {
    float s2 = t0 + t1, q2 = t0 * t0 + t1 * t1;
    breduce2(s2, q2, red);
    const float mu2 = s2 * (1.0f / Dd);
    const float var2 = q2 * (1.0f / Dd) - mu2 * mu2;
    const float rs2 = rsqrtf(var2 + 1e-5f);
    const float o0 = (t0 - mu2) * rs2 * g2[d0]     + b2v[d0];
    const float o1 = (t1 - mu2) * rs2 * g2[d0 + 1] + b2v[d0 + 1];
    *(float2*)(outf + (size_t)row * Dd + d0) = make_float2(o0, o1);
  } else {
    bf16x2 ov; ov[0] = (__bf16)t0; ov[1] = (__bf16)t1;
    *(bf16x2*)(outb + (size_t)row * Dd + d0) = ov;
  }
}

// ------------------------------------------------------------------ launch
extern "C" void kernel_launch(void* const* d_in, const int* in_sizes, int n_in,
                              void* d_out, int out_size, void* d_ws, size_t ws_size,
                              hipStream_t stream) {
  const float* feats = (const float*)d_in[0];
  const float* W1    = (const float*)d_in[2];
  const float* ln1_g = (const float*)d_in[3];
  const float* ln1_b = (const float*)d_in[4];
  const float* W2    = (const float*)d_in[5];
  const float* ln2_g = (const float*)d_in[6];
  const float* ln2_b = (const float*)d_in[7];
  const float* out_g = (const float*)d_in[8];
  const float* out_b = (const float*)d_in[9];
  float* out = (float*)d_out;

  char* w = (char*)d_ws;
  float* rinv = (float*)w; w += (size_t)BN * 4;
  float* topv = (float*)w; w += (size_t)BN * KTOP * 4;
  int*   topi = (int*)w;   w += (size_t)BN * KTOP * 4;
  int*   ecnt = (int*)w;   w += (size_t)BN * 4;
  int*   eidx = (int*)w;   w += (size_t)BN * CAP * 4;
  float* ew   = (float*)w; w += (size_t)BN * CAP * 4;
  float* dis  = (float*)w; w += (size_t)BN * 4;
  __bf16* Wt1 = (__bf16*)w; w += (size_t)Dd * Dd * 2;
  __bf16* Wt2 = (__bf16*)w; w += (size_t)Dd * Dd * 2;
  float* ybuf = (float*)w; w += (size_t)BN * Dd * 4;   // 32 MB
  __bf16* xb  = (__bf16*)w; w += (size_t)BN * Dd * 2;  // 16 MB
  __bf16* h1b = (__bf16*)w; w += (size_t)BN * Dd * 2;  // 16 MB
  __bf16* Hg = (__bf16*)ybuf;                          // overlay (dead before gemm1)
  __bf16* Lg = Hg + (size_t)BN * Dd;
  float* pv  = (float*)h1b;                            // overlay (dead before agg1)
  int*   pi  = (int*)((char*)h1b + (size_t)BN * NSLICE * 8 * 4);

  hipMemsetAsync(ecnt, 0, (size_t)BN * 4, stream);

  rownorm_kernel<<<BN / 4, 256, 0, stream>>>(feats, rinv);
  split_kernel<<<(BN * Dd) / (4 * 256), 256, 0, stream>>>(feats, rinv, Hg, Lg, xb);
  wcast_t<<<dim3(16, 16), 256, 0, stream>>>(W1, Wt1);
  wcast_t<<<dim3(16, 16), 256, 0, stream>>>(W2, Wt2);

  sim_mfma_topk<<<dim3(Nn / 128, NSLICE, Bb), 256, 0, stream>>>(Hg, Lg, pv, pi);
  merge_topk<<<BN / 256, 256, 0, stream>>>(pv, pi, topv, topi);
  build_edges_kernel<<<BN / 256, 256, 0, stream>>>(topv, topi, ecnt, eidx, ew);
  deg_kernel<<<BN / 256, 256, 0, stream>>>(ecnt, ew, dis);

  gemm_mfma<<<dim3(BN / 128, Dd / 128), 256, 0, stream>>>(xb, Wt1, ybuf);
  agg_ln_kernel<false><<<BN, 256, 0, stream>>>(ybuf, feats, nullptr, ecnt, eidx, ew, dis,
                                               ln1_g, ln1_b, nullptr, nullptr,
                                               nullptr, h1b);
  gemm_mfma<<<dim3(BN / 128, Dd / 128), 256, 0, stream>>>(h1b, Wt2, ybuf);
  agg_ln_kernel<true><<<BN, 256, 0, stream>>>(ybuf, nullptr, h1b, ecnt, eidx, ew, dis,
                                              ln2_g, ln2_b, out_g, out_b,
                                              out, nullptr);
}

// Round 5
// 528.925 us; speedup vs baseline: 1.0864x; 1.0864x over previous
//
#include <hip/hip_runtime.h>
#include <cstdint>

// ---------------------------------------------------------------------------
// SimilarityGCNEncoder: B=8, N=2048, D=512, fp32.
//   sim_mfma_topk: split-bf16 MFMA cos-sim + fused top-8, dbuf counted-vmcnt
//   pipeline. NEW (r5): XCD-affinity swizzle — flat%8 == batch, so each XCD's
//   working set (one batch's H+L = 4 MB) is exactly its L2. Kills the 280 MB
//   cross-XCD panel re-fetch seen in r4 counters.
//   agg_ln: same batch->XCD swizzle (y-gather becomes L2-served).
// ---------------------------------------------------------------------------

constexpr int Bb   = 8;
constexpr int Nn   = 2048;
constexpr int Dd   = 512;
constexpr int BN   = Bb * Nn;
constexpr int KTOP = 8;
constexpr int CAP  = 56;
constexpr int NSLICE = 4;

typedef __attribute__((ext_vector_type(8))) __bf16 bf16x8;
typedef __attribute__((ext_vector_type(4))) __bf16 bf16x4;
typedef __attribute__((ext_vector_type(2))) __bf16 bf16x2;
typedef __attribute__((ext_vector_type(4))) float  f32x4;

__device__ __forceinline__ void gload16(const void* g, void* l) {
  __builtin_amdgcn_global_load_lds((const __attribute__((address_space(1))) unsigned int*)g,
                                   (__attribute__((address_space(3))) unsigned int*)l,
                                   16, 0, 0);
}
__device__ __forceinline__ void barrier_raw() {
  asm volatile("" ::: "memory");
  __builtin_amdgcn_s_barrier();
  asm volatile("" ::: "memory");
}
__device__ __forceinline__ void barrier_lds() {       // after ds_write producers
  asm volatile("s_waitcnt lgkmcnt(0)" ::: "memory");
  __builtin_amdgcn_s_barrier();
  asm volatile("" ::: "memory");
}

// ---------------------------------------------------------------- row norms
__global__ __launch_bounds__(256) void rownorm_kernel(const float* __restrict__ feats,
                                                      float* __restrict__ rinv) {
  const int row  = blockIdx.x * 4 + (threadIdx.x >> 6);
  const int lane = threadIdx.x & 63;
  const float* p = feats + (size_t)row * Dd + lane * 8;
  float4 a = *(const float4*)p;
  float4 b = *(const float4*)(p + 4);
  float s = a.x*a.x + a.y*a.y + a.z*a.z + a.w*a.w
          + b.x*b.x + b.y*b.y + b.z*b.z + b.w*b.w;
#pragma unroll
  for (int o = 32; o; o >>= 1) s += __shfl_down(s, o);
  if (lane == 0) rinv[row] = 1.0f / fmaxf(sqrtf(s), 1e-8f);
}

// ------------------------------------------------------- hi/lo split + cast
__global__ __launch_bounds__(256) void split_kernel(const float* __restrict__ feats,
                                                    const float* __restrict__ rinv,
                                                    __bf16* __restrict__ H,
                                                    __bf16* __restrict__ L,
                                                    __bf16* __restrict__ Xb) {
  const size_t base = ((size_t)blockIdx.x * 256 + threadIdx.x) * 4;
  const float s = rinv[base >> 9];
  float4 x = *(const float4*)(feats + base);
  float xs[4] = {x.x, x.y, x.z, x.w};
  bf16x4 hv, lv, xv;
#pragma unroll
  for (int j = 0; j < 4; ++j) {
    xv[j] = (__bf16)xs[j];
    const float n = xs[j] * s;
    const __bf16 h = (__bf16)n;
    hv[j] = h;
    lv[j] = (__bf16)(n - (float)h);
  }
  *(bf16x4*)(H + base) = hv;
  *(bf16x4*)(L + base) = lv;
  *(bf16x4*)(Xb + base) = xv;
}

// ------------------------------------------------- W cast + transpose (bf16)
__global__ __launch_bounds__(256) void wcast_t(const float* __restrict__ W,
                                               __bf16* __restrict__ Wt) {
  __shared__ float t[32][33];
  const int bx = blockIdx.x * 32, by = blockIdx.y * 32;
  const int lx = threadIdx.x & 31, ly = threadIdx.x >> 5;
#pragma unroll
  for (int r = 0; r < 32; r += 8)
    t[ly + r][lx] = W[(size_t)(by + ly + r) * Dd + bx + lx];
  __syncthreads();
#pragma unroll
  for (int r = 0; r < 32; r += 8)
    Wt[(size_t)(bx + ly + r) * Dd + by + lx] = (__bf16)t[lx][ly + r];
}

// ----------------------------------------------------- top-8 insert helper
__device__ __forceinline__ void ins8(float (&tv)[8], int (&ti)[8], float v, int idx) {
#pragma unroll
  for (int q = 0; q < 8; ++q) {
    bool sw = v > tv[q];
    float a = sw ? tv[q] : v;
    int   c = sw ? ti[q] : idx;
    tv[q] = sw ? v   : tv[q];
    ti[q] = sw ? idx : ti[q];
    v = a; idx = c;
  }
}

// ------------------------------------------- split-bf16 MFMA sim + top-8
// Flat grid 512; decode so flat%8 == batch -> batch z pinned to XCD z under
// round-robin dispatch; per-XCD working set = that batch's H+L = 4 MB = L2.
__global__ __launch_bounds__(256, 2) void sim_mfma_topk(const __bf16* __restrict__ Hg,
                                                        const __bf16* __restrict__ Lg,
                                                        float* __restrict__ pv,
                                                        int* __restrict__ pi) {
  __shared__ __align__(16) char smem[81920];
  float* Ssh = (float*)(smem + 65536);      // [128][32] fp32, XOR-swizzled

  const int f     = blockIdx.x;
  const int bz    = f & 7;                  // batch == XCD id
  const int rr    = f >> 3;                 // 0..63
  const int r0    = (rr & 15) * 128;        // row tile
  const int slice = rr >> 4;                // 0..3

  const int tid    = threadIdx.x;
  const int lane   = tid & 63;
  const int lane15 = tid & 15;
  const int kgrp   = (tid >> 4) & 3;
  const int wv     = tid >> 6;
  const int wrow0  = wv * 32;
  const int bN     = bz * Nn;

  const __bf16* HgA  = Hg + (size_t)(bN + r0) * Dd;
  const __bf16* LgA  = Lg + (size_t)(bN + r0) * Dd;
  const __bf16* HgB0 = Hg + (size_t)(bN + slice * 512) * Dd;
  const __bf16* LgB0 = Lg + (size_t)(bN + slice * 512) * Dd;

  const int srow  = tid >> 1;
  const int shalf = tid & 1;
  const int rowg  = r0 + srow;
  float t8v[8]; int t8i[8];
#pragma unroll
  for (int q = 0; q < 8; ++q) { t8v[q] = -1.0f; t8i[q] = 0; }

  // wave wv stages one region per step: 0=AH 1=AL 2=BH 3=BL
  auto stage = [&](int t, int buf) {
    const int ct = t >> 4, kb = (t & 15) << 5;
    const __bf16* wbase =
        wv == 0 ? HgA : wv == 1 ? LgA
      : (wv == 2 ? HgB0 : LgB0) + (size_t)ct * 128 * Dd;
    char* ldsb = smem + buf * 32768 + wv * 8192;
#pragma unroll
    for (int i = 0; i < 8; ++i) {
      const int kg = i >> 1, rb = (i & 1) << 6;
      gload16(wbase + (size_t)(rb + lane) * Dd + kb + kg * 8,
              ldsb + kg * 2048 + rb * 16);
    }
  };

  f32x4 acc[2][8];
  const f32x4 z = {0.f, 0.f, 0.f, 0.f};

  stage(0, 0);
  for (int t = 0; t < 64; ++t) {
    const int cur = t & 1;
    if ((t & 15) == 0) {
#pragma unroll
      for (int i = 0; i < 2; ++i)
#pragma unroll
        for (int j = 0; j < 8; ++j) acc[i][j] = z;
    }
    if (t + 1 < 64) {
      stage(t + 1, cur ^ 1);
      asm volatile("s_waitcnt vmcnt(8)" ::: "memory");   // prev 8 done; 8 in flight
    } else {
      asm volatile("s_waitcnt vmcnt(0)" ::: "memory");
    }
    barrier_raw();                           // everyone's cur-buffer complete

    const char* sb = smem + cur * 32768;
    const int a0o = kgrp * 2048 + (wrow0 + lane15) * 16;
    bf16x8 ah0 = *(const bf16x8*)(sb + a0o);
    bf16x8 ah1 = *(const bf16x8*)(sb + a0o + 256);
    bf16x8 al0 = *(const bf16x8*)(sb + 8192 + a0o);
    bf16x8 al1 = *(const bf16x8*)(sb + 8192 + a0o + 256);
#pragma unroll
    for (int cs = 0; cs < 8; ++cs) {
      const int bo = kgrp * 2048 + (cs * 16 + lane15) * 16;
      bf16x8 bh = *(const bf16x8*)(sb + 16384 + bo);
      bf16x8 bl = *(const bf16x8*)(sb + 24576 + bo);
      acc[0][cs] = __builtin_amdgcn_mfma_f32_16x16x32_bf16(ah0, bh, acc[0][cs], 0, 0, 0);
      acc[0][cs] = __builtin_amdgcn_mfma_f32_16x16x32_bf16(ah0, bl, acc[0][cs], 0, 0, 0);
      acc[0][cs] = __builtin_amdgcn_mfma_f32_16x16x32_bf16(al0, bh, acc[0][cs], 0, 0, 0);
      acc[1][cs] = __builtin_amdgcn_mfma_f32_16x16x32_bf16(ah1, bh, acc[1][cs], 0, 0, 0);
      acc[1][cs] = __builtin_amdgcn_mfma_f32_16x16x32_bf16(ah1, bl, acc[1][cs], 0, 0, 0);
      acc[1][cs] = __builtin_amdgcn_mfma_f32_16x16x32_bf16(al1, bh, acc[1][cs], 0, 0, 0);
    }
    barrier_raw();                           // all waves done reading cur buffer

    if ((t & 15) == 15) {                    // tile done -> chunked scan
      const int ct = t >> 4;
      const int ctile0 = slice * 512 + ct * 128;
#pragma unroll
      for (int ch = 0; ch < 4; ++ch) {       // static ch -> static acc indices
#pragma unroll
        for (int rs = 0; rs < 2; ++rs)
#pragma unroll
          for (int p = 0; p < 2; ++p) {
            const int cs = ch * 2 + p;
#pragma unroll
            for (int e = 0; e < 4; ++e) {
              const int row = wrow0 + rs * 16 + kgrp * 4 + e;
              const int col = p * 16 + lane15;
              Ssh[row * 32 + (col ^ ((row & 7) << 2))] = acc[rs][cs][e];
            }
          }
        barrier_lds();
        const int cbase = ctile0 + ch * 32 + shalf * 16;
        const int sw = (srow & 7) << 2;
#pragma unroll
        for (int c = 0; c < 16; ++c) {
          const float raw = Ssh[srow * 32 + ((shalf * 16 + c) ^ sw)];
          const float v = (raw + 1.0f) * 0.5f;
          const int gcol = cbase + c;
          if (gcol != rowg && v > t8v[7]) ins8(t8v, t8i, v, gcol);
        }
        barrier_raw();
      }
    }
  }

  // merge the two col-half partials per row, write slice partial
  float* Mv = Ssh;                            // [128][8]
  int*   Mi = (int*)(smem + 65536 + 4096);
  if (shalf) {
#pragma unroll
    for (int q = 0; q < 8; ++q) { Mv[srow * 8 + q] = t8v[q]; Mi[srow * 8 + q] = t8i[q]; }
  }
  barrier_lds();
  if (!shalf) {
#pragma unroll
    for (int q = 0; q < 8; ++q) {
      const float v = Mv[srow * 8 + q];
      if (v > t8v[7]) ins8(t8v, t8i, v, Mi[srow * 8 + q]);
    }
    const int prow = bN + rowg;
#pragma unroll
    for (int q = 0; q < 8; ++q) {
      pv[(prow * NSLICE + slice) * 8 + q] = t8v[q];
      pi[(prow * NSLICE + slice) * 8 + q] = bN + t8i[q];
    }
  }
}

// ----------------------------------------------------- merge slice partials
__global__ __launch_bounds__(256) void merge_topk(const float* __restrict__ pv,
                                                  const int* __restrict__ pi,
                                                  float* __restrict__ topv,
                                                  int* __restrict__ topi) {
  const int row = blockIdx.x * 256 + threadIdx.x;
  if (row >= BN) return;
  float tv[8]; int ti[8];
#pragma unroll
  for (int q = 0; q < 8; ++q) { tv[q] = -1.0f; ti[q] = 0; }
  for (int s = 0; s < NSLICE; ++s)
#pragma unroll
    for (int q = 0; q < 8; ++q) {
      const float v = pv[(row * NSLICE + s) * 8 + q];
      if (v > tv[7]) ins8(tv, ti, v, pi[(row * NSLICE + s) * 8 + q]);
    }
#pragma unroll
  for (int q = 0; q < 8; ++q) { topv[row * 8 + q] = tv[q]; topi[row * 8 + q] = ti[q]; }
}

// ------------------------------------------------------------- build edges
__global__ __launch_bounds__(256) void build_edges_kernel(const float* __restrict__ topv,
                                                          const int* __restrict__ topi,
                                                          int* __restrict__ ecnt,
                                                          int* __restrict__ eidx,
                                                          float* __restrict__ ew) {
  const int r = blockIdx.x * 256 + threadIdx.x;
  if (r >= BN) return;
#pragma unroll
  for (int t = 0; t < KTOP; ++t) {
    const float v = topv[r * KTOP + t];
    if (v > 0.0f) {
      const int j = topi[r * KTOP + t];
      const float w = 0.5f * v;
      int p = atomicAdd(&ecnt[r], 1);
      if (p < CAP) { eidx[r * CAP + p] = j; ew[r * CAP + p] = w; }
      int q = atomicAdd(&ecnt[j], 1);
      if (q < CAP) { eidx[j * CAP + q] = r; ew[j * CAP + q] = w; }
    }
  }
}

// ------------------------------------------------------------------ degree
__global__ __launch_bounds__(256) void deg_kernel(const int* __restrict__ ecnt,
                                                  const float* __restrict__ ew,
                                                  float* __restrict__ dis) {
  const int r = blockIdx.x * 256 + threadIdx.x;
  if (r >= BN) return;
  const int cnt = min(ecnt[r], CAP);
  float d = 1.0f;
  for (int e = 0; e < cnt; ++e) d += ew[r * CAP + e];
  dis[r] = rsqrtf(fmaxf(d, 1e-8f));
}

// ----------------------------------------------- y = x @ W via bf16 MFMA
__global__ __launch_bounds__(256, 2) void gemm_mfma(const __bf16* __restrict__ Xb,
                                                    const __bf16* __restrict__ Wt,
                                                    float* __restrict__ Y) {
  __shared__ __align__(16) char smem[32768];
  const int tid    = threadIdx.x;
  const int lane   = tid & 63;
  const int lane15 = tid & 15;
  const int kgrp   = (tid >> 4) & 3;
  const int wv     = tid >> 6;
  const int m0 = blockIdx.x * 128, n0 = blockIdx.y * 128;

  auto stage = [&](int t, int buf) {
    const int kb = t << 5;
#pragma unroll
    for (int i = 0; i < 4; ++i) {
      const int c = (wv << 2) + i;           // 0..15: 0-7 X, 8-15 Wt
      const int kg = (c & 7) >> 1, rb = (c & 1) << 6;
      const __bf16* g = (c >> 3)
          ? Wt + (size_t)(n0 + rb + lane) * Dd + kb + kg * 8
          : Xb + (size_t)(m0 + rb + lane) * Dd + kb + kg * 8;
      gload16(g, smem + buf * 16384 + ((c >> 3) << 13) + kg * 2048 + rb * 16);
    }
  };

  f32x4 acc[2][8];
  const f32x4 z = {0.f, 0.f, 0.f, 0.f};
#pragma unroll
  for (int i = 0; i < 2; ++i)
#pragma unroll
    for (int j = 0; j < 8; ++j) acc[i][j] = z;

  stage(0, 0);
  for (int t = 0; t < 16; ++t) {
    const int cur = t & 1;
    if (t + 1 < 16) {
      stage(t + 1, cur ^ 1);
      asm volatile("s_waitcnt vmcnt(4)" ::: "memory");
    } else {
      asm volatile("s_waitcnt vmcnt(0)" ::: "memory");
    }
    barrier_raw();

    const char* sb = smem + cur * 16384;
    const int a0o = kgrp * 2048 + (wv * 32 + lane15) * 16;
    bf16x8 a0 = *(const bf16x8*)(sb + a0o);
    bf16x8 a1 = *(const bf16x8*)(sb + a0o + 256);
#pragma unroll
    for (int cs = 0; cs < 8; ++cs) {
      bf16x8 b = *(const bf16x8*)(sb + 8192 + kgrp * 2048 + (cs * 16 + lane15) * 16);
      acc[0][cs] = __builtin_amdgcn_mfma_f32_16x16x32_bf16(a0, b, acc[0][cs], 0, 0, 0);
      acc[1][cs] = __builtin_amdgcn_mfma_f32_16x16x32_bf16(a1, b, acc[1][cs], 0, 0, 0);
    }
    barrier_raw();
  }
  const int rgrp = lane >> 4;
#pragma unroll
  for (int rs = 0; rs < 2; ++rs)
#pragma unroll
    for (int cs = 0; cs < 8; ++cs)
#pragma unroll
      for (int e = 0; e < 4; ++e) {
        const int row = m0 + wv * 32 + rs * 16 + rgrp * 4 + e;
        const int col = n0 + cs * 16 + lane15;
        Y[(size_t)row * Dd + col] = acc[rs][cs][e];
      }
}

// -------------------------------------------------- aggregation + LN (+LN)
__device__ inline void breduce2(float& s, float& q, float* red) {
#pragma unroll
  for (int o = 32; o; o >>= 1) { s += __shfl_down(s, o); q += __shfl_down(q, o); }
  const int wid = threadIdx.x >> 6, lane = threadIdx.x & 63;
  if (lane == 0) { red[wid * 2] = s; red[wid * 2 + 1] = q; }
  __syncthreads();
  if (threadIdx.x == 0) {
    float S = 0.f, Q = 0.f;
#pragma unroll
    for (int w2 = 0; w2 < 4; ++w2) { S += red[w2 * 2]; Q += red[w2 * 2 + 1]; }
    red[8] = S; red[9] = Q;
  }
  __syncthreads();
  s = red[8]; q = red[9];
}

template <bool FINAL>
__global__ __launch_bounds__(256) void agg_ln_kernel(const float* __restrict__ y,
                                                     const float* __restrict__ xres_f,
                                                     const __bf16* __restrict__ xres_b,
                                                     const int* __restrict__ ecnt,
                                                     const int* __restrict__ eidx,
                                                     const float* __restrict__ ew,
                                                     const float* __restrict__ dis,
                                                     const float* __restrict__ g1,
                                                     const float* __restrict__ b1v,
                                                     const float* __restrict__ g2,
                                                     const float* __restrict__ b2v,
                                                     float* __restrict__ outf,
                                                     __bf16* __restrict__ outb) {
  __shared__ float red[10];
  // batch -> XCD affinity: row's batch == flat%8, so the y-gather (all
  // neighbors j are same-batch, 4 MB fp32) is served by this XCD's L2.
  const int row = (blockIdx.x & 7) * Nn + (blockIdx.x >> 3);
  const int tid = threadIdx.x;
  const int d0 = tid * 2;
  const float di = dis[row];

  float2 yv = *(const float2*)(y + (size_t)row * Dd + d0);
  float a0 = di * di * yv.x, a1 = di * di * yv.y;
  const int cnt = min(ecnt[row], CAP);
  for (int e = 0; e < cnt; ++e) {
    const int j = eidx[row * CAP + e];
    const float c = ew[row * CAP + e] * di * dis[j];
    float2 v = *(const float2*)(y + (size_t)j * Dd + d0);
    a0 += c * v.x; a1 += c * v.y;
  }
  if (FINAL) {
    const unsigned short* xp = (const unsigned short*)xres_b + (size_t)row * Dd + d0;
    ushort2 u = *(const ushort2*)xp;
    a0 += __uint_as_float((unsigned)u.x << 16);
    a1 += __uint_as_float((unsigned)u.y << 16);
  } else {
    float2 xv = *(const float2*)(xres_f + (size_t)row * Dd + d0);
    a0 += xv.x; a1 += xv.y;
  }

  float s = a0 + a1, q = a0 * a0 + a1 * a1;
  breduce2(s, q, red);
  const float mu = s * (1.0f / Dd);
  const float var = q * (1.0f / Dd) - mu * mu;
  const float rs = rsqrtf(var + 1e-5f);
  float t0 = fmaxf((a0 - mu) * rs * g1[d0]     + b1v[d0],     0.0f);
  float t1 = fmaxf((a1 - mu) * rs * g1[d0 + 1] + b1v[d0 + 1], 0.0f);

  if (FINAL) {
    float s2 = t0 + t1, q2 = t0 * t0 + t1 * t1;
    breduce2(s2, q2, red);
    const float mu2 = s2 * (1.0f / Dd);
    const float var2 = q2 * (1.0f / Dd) - mu2 * mu2;
    const float rs2 = rsqrtf(var2 + 1e-5f);
    const float o0 = (t0 - mu2) * rs2 * g2[d0]     + b2v[d0];
    const float o1 = (t1 - mu2) * rs2 * g2[d0 + 1] + b2v[d0 + 1];
    *(float2*)(outf + (size_t)row * Dd + d0) = make_float2(o0, o1);
  } else {
    bf16x2 ov; ov[0] = (__bf16)t0; ov[1] = (__bf16)t1;
    *(bf16x2*)(outb + (size_t)row * Dd + d0) = ov;
  }
}

// ------------------------------------------------------------------ launch
extern "C" void kernel_launch(void* const* d_in, const int* in_sizes, int n_in,
                              void* d_out, int out_size, void* d_ws, size_t ws_size,
                              hipStream_t stream) {
  const float* feats = (const float*)d_in[0];
  const float* W1    = (const float*)d_in[2];
  const float* ln1_g = (const float*)d_in[3];
  const float* ln1_b = (const float*)d_in[4];
  const float* W2    = (const float*)d_in[5];
  const float* ln2_g = (const float*)d_in[6];
  const float* ln2_b = (const float*)d_in[7];
  const float* out_g = (const float*)d_in[8];
  const float* out_b = (const float*)d_in[9];
  float* out = (float*)d_out;

  char* w = (char*)d_ws;
  float* rinv = (float*)w; w += (size_t)BN * 4;
  float* topv = (float*)w; w += (size_t)BN * KTOP * 4;
  int*   topi = (int*)w;   w += (size_t)BN * KTOP * 4;
  int*   ecnt = (int*)w;   w += (size_t)BN * 4;
  int*   eidx = (int*)w;   w += (size_t)BN * CAP * 4;
  float* ew   = (float*)w; w += (size_t)BN * CAP * 4;
  float* dis  = (float*)w; w += (size_t)BN * 4;
  __bf16* Wt1 = (__bf16*)w; w += (size_t)Dd * Dd * 2;
  __bf16* Wt2 = (__bf16*)w; w += (size_t)Dd * Dd * 2;
  float* ybuf = (float*)w; w += (size_t)BN * Dd * 4;   // 32 MB
  __bf16* xb  = (__bf16*)w; w += (size_t)BN * Dd * 2;  // 16 MB
  __bf16* h1b = (__bf16*)w; w += (size_t)BN * Dd * 2;  // 16 MB
  __bf16* Hg = (__bf16*)ybuf;                          // overlay (dead before gemm1)
  __bf16* Lg = Hg + (size_t)BN * Dd;
  float* pv  = (float*)h1b;                            // overlay (dead before agg1)
  int*   pi  = (int*)((char*)h1b + (size_t)BN * NSLICE * 8 * 4);

  hipMemsetAsync(ecnt, 0, (size_t)BN * 4, stream);

  rownorm_kernel<<<BN / 4, 256, 0, stream>>>(feats, rinv);
  split_kernel<<<(BN * Dd) / (4 * 256), 256, 0, stream>>>(feats, rinv, Hg, Lg, xb);
  wcast_t<<<dim3(16, 16), 256, 0, stream>>>(W1, Wt1);
  wcast_t<<<dim3(16, 16), 256, 0, stream>>>(W2, Wt2);

  sim_mfma_topk<<<512, 256, 0, stream>>>(Hg, Lg, pv, pi);
  merge_topk<<<BN / 256, 256, 0, stream>>>(pv, pi, topv, topi);
  build_edges_kernel<<<BN / 256, 256, 0, stream>>>(topv, topi, ecnt, eidx, ew);
  deg_kernel<<<BN / 256, 256, 0, stream>>>(ecnt, ew, dis);

  gemm_mfma<<<dim3(BN / 128, Dd / 128), 256, 0, stream>>>(xb, Wt1, ybuf);
  agg_ln_kernel<false><<<BN, 256, 0, stream>>>(ybuf, feats, nullptr, ecnt, eidx, ew, dis,
                                               ln1_g, ln1_b, nullptr, nullptr,
                                               nullptr, h1b);
  gemm_mfma<<<dim3(BN / 128, Dd / 128), 256, 0, stream>>>(h1b, Wt2, ybuf);
  agg_ln_kernel<true><<<BN, 256, 0, stream>>>(ybuf, nullptr, h1b, ecnt, eidx, ew, dis,
                                              ln2_g, ln2_b, out_g, out_b,
                                              out, nullptr);
}

// Round 6
// 386.983 us; speedup vs baseline: 1.4849x; 1.3668x over previous
//
#include <hip/hip_runtime.h>
#include <cstdint>

// ---------------------------------------------------------------------------
// SimilarityGCNEncoder: B=8, N=2048, D=512, fp32.
// r6: k-major global layouts for ALL MFMA operands so global_load_lds staging
// is fully coalesced (r5 evidence: duration invariant across memory tiers ->
// VMEM line-request-rate bound; row-major staging = 64 lines/instr, k-major
// = 16). LDS layouts and compute unchanged from r5.
//   Hk/Lk : [b][k8=64][n=2048][8]  (normalized hi/lo split, per batch)
//   Xk/h1k: [k8=64][row=BN][8]     (gemm A operands)
//   Wk    : [k8=64][n=512][8]      (gemm B operand)
// ---------------------------------------------------------------------------

constexpr int Bb   = 8;
constexpr int Nn   = 2048;
constexpr int Dd   = 512;
constexpr int BN   = Bb * Nn;
constexpr int KTOP = 8;
constexpr int CAP  = 56;
constexpr int NSLICE = 4;

typedef __attribute__((ext_vector_type(8))) __bf16 bf16x8;
typedef __attribute__((ext_vector_type(2))) __bf16 bf16x2;
typedef __attribute__((ext_vector_type(4))) float  f32x4;

__device__ __forceinline__ void gload16(const void* g, void* l) {
  __builtin_amdgcn_global_load_lds((const __attribute__((address_space(1))) unsigned int*)g,
                                   (__attribute__((address_space(3))) unsigned int*)l,
                                   16, 0, 0);
}
__device__ __forceinline__ void barrier_raw() {
  asm volatile("" ::: "memory");
  __builtin_amdgcn_s_barrier();
  asm volatile("" ::: "memory");
}
__device__ __forceinline__ void barrier_lds() {
  asm volatile("s_waitcnt lgkmcnt(0)" ::: "memory");
  __builtin_amdgcn_s_barrier();
  asm volatile("" ::: "memory");
}

// ---------------------------------------------------------------- row norms
__global__ __launch_bounds__(256) void rownorm_kernel(const float* __restrict__ feats,
                                                      float* __restrict__ rinv) {
  const int row  = blockIdx.x * 4 + (threadIdx.x >> 6);
  const int lane = threadIdx.x & 63;
  const float* p = feats + (size_t)row * Dd + lane * 8;
  float4 a = *(const float4*)p;
  float4 b = *(const float4*)(p + 4);
  float s = a.x*a.x + a.y*a.y + a.z*a.z + a.w*a.w
          + b.x*b.x + b.y*b.y + b.z*b.z + b.w*b.w;
#pragma unroll
  for (int o = 32; o; o >>= 1) s += __shfl_down(s, o);
  if (lane == 0) rinv[row] = 1.0f / fmaxf(sqrtf(s), 1e-8f);
}

// --------------------------- split + cast, k-major outputs (LDS transpose)
// Block: 64 rows x 512 k, in 8 tiles of 64 k. Coalesced loads, coalesced
// 16B-chunk writes to Hk/Lk/Xk.
__global__ __launch_bounds__(256) void split_kernel(const float* __restrict__ feats,
                                                    const float* __restrict__ rinv,
                                                    __bf16* __restrict__ Hk,
                                                    __bf16* __restrict__ Lk,
                                                    __bf16* __restrict__ Xk) {
  __shared__ float tile[64][65];
  __shared__ float rsh[64];
  const int r0 = blockIdx.x * 64;          // global row base
  const int bz = r0 >> 11;                 // batch
  const int n0 = r0 & 2047;                // row within batch
  const int t  = threadIdx.x;
  if (t < 64) rsh[t] = rinv[r0 + t];

  for (int kt = 0; kt < 8; ++kt) {
    __syncthreads();                       // prior reads done / rsh ready
#pragma unroll
    for (int p = 0; p < 4; ++p) {          // 16 rows x 16 float4 per pass
      const int row = p * 16 + (t >> 4), ch = t & 15;
      float4 v = *(const float4*)(feats + (size_t)(r0 + row) * Dd + kt * 64 + ch * 4);
      tile[row][ch * 4 + 0] = v.x; tile[row][ch * 4 + 1] = v.y;
      tile[row][ch * 4 + 2] = v.z; tile[row][ch * 4 + 3] = v.w;
    }
    __syncthreads();
#pragma unroll
    for (int h = 0; h < 2; ++h) {          // 512 chunks: (8 k8) x (64 rows)
      const int c = h * 256 + t;
      const int k8l = c >> 6, row = c & 63;
      const float s = rsh[row];
      bf16x8 hv, lv, xv;
#pragma unroll
      for (int e = 0; e < 8; ++e) {
        const float x = tile[row][k8l * 8 + e];
        xv[e] = (__bf16)x;
        const float nm = x * s;
        const __bf16 hh = (__bf16)nm;
        hv[e] = hh;
        lv[e] = (__bf16)(nm - (float)hh);
      }
      const size_t kk = (size_t)(kt * 8 + k8l);
      *(bf16x8*)(Hk + ((size_t)(bz * 64) + kk) * (Nn * 8) + (n0 + row) * 8) = hv;
      *(bf16x8*)(Lk + ((size_t)(bz * 64) + kk) * (Nn * 8) + (n0 + row) * 8) = lv;
      *(bf16x8*)(Xk + kk * ((size_t)BN * 8) + (size_t)(r0 + row) * 8) = xv;
    }
  }
}

// --------------------------------- W cast -> k-major Wk[k8][n=512][8] bf16
__global__ __launch_bounds__(256) void wcast_t(const float* __restrict__ W,
                                               __bf16* __restrict__ Wk) {
  __shared__ float t[32][33];
  const int bx = blockIdx.x * 32, by = blockIdx.y * 32;   // bx=n, by=k
  const int lx = threadIdx.x & 31, ly = threadIdx.x >> 5;
#pragma unroll
  for (int r = 0; r < 32; r += 8)
    t[ly + r][lx] = W[(size_t)(by + ly + r) * Dd + bx + lx];
  __syncthreads();
  if (threadIdx.x < 128) {
    const int k8l = threadIdx.x >> 5, nl = threadIdx.x & 31;
    bf16x8 v;
#pragma unroll
    for (int e = 0; e < 8; ++e) v[e] = (__bf16)t[k8l * 8 + e][nl];
    *(bf16x8*)(Wk + ((size_t)((by >> 3) + k8l) * Dd + bx + nl) * 8) = v;
  }
}

// ----------------------------------------------------- top-8 insert helper
__device__ __forceinline__ void ins8(float (&tv)[8], int (&ti)[8], float v, int idx) {
#pragma unroll
  for (int q = 0; q < 8; ++q) {
    bool sw = v > tv[q];
    float a = sw ? tv[q] : v;
    int   c = sw ? ti[q] : idx;
    tv[q] = sw ? v   : tv[q];
    ti[q] = sw ? idx : ti[q];
    v = a; idx = c;
  }
}

// ------------------------------------------- split-bf16 MFMA sim + top-8
// flat%8 == batch (XCD affinity, r5). Staging now coalesced from k-major
// Hk/Lk: one gload16 = contiguous 1KB.
__global__ __launch_bounds__(256, 2) void sim_mfma_topk(const __bf16* __restrict__ Hk,
                                                        const __bf16* __restrict__ Lk,
                                                        float* __restrict__ pv,
                                                        int* __restrict__ pi) {
  __shared__ __align__(16) char smem[81920];
  float* Ssh = (float*)(smem + 65536);      // [128][32] fp32, XOR-swizzled

  const int f     = blockIdx.x;
  const int bz    = f & 7;                  // batch == XCD id
  const int rr    = f >> 3;
  const int r0    = (rr & 15) * 128;
  const int slice = rr >> 4;

  const int tid    = threadIdx.x;
  const int lane   = tid & 63;
  const int lane15 = tid & 15;
  const int kgrp   = (tid >> 4) & 3;
  const int wv     = tid >> 6;
  const int wrow0  = wv * 32;
  const int bN     = bz * Nn;

  const __bf16* Hb = Hk + (size_t)(bz * 64) * (Nn * 8);   // batch base
  const __bf16* Lb = Lk + (size_t)(bz * 64) * (Nn * 8);

  const int srow  = tid >> 1;
  const int shalf = tid & 1;
  const int rowg  = r0 + srow;
  float t8v[8]; int t8i[8];
#pragma unroll
  for (int q = 0; q < 8; ++q) { t8v[q] = -1.0f; t8i[q] = 0; }

  // wave wv stages one region per step: 0=AH 1=AL 2=BH 3=BL
  auto stage = [&](int t, int buf) {
    const int ct = t >> 4, k80 = (t & 15) << 2;            // k8 base (4 kgroups)
    const int rbase = (wv < 2) ? r0 : slice * 512 + ct * 128;
    const __bf16* base = ((wv & 1) == 0) ? Hb : Lb;
    char* ldsb = smem + buf * 32768 + wv * 8192;
#pragma unroll
    for (int i = 0; i < 8; ++i) {
      const int kg = i >> 1, rb = (i & 1) << 6;
      gload16(base + ((size_t)(k80 + kg) * Nn + rbase + rb + lane) * 8,
              ldsb + kg * 2048 + rb * 16);
    }
  };

  f32x4 acc[2][8];
  const f32x4 z = {0.f, 0.f, 0.f, 0.f};

  stage(0, 0);
  for (int t = 0; t < 64; ++t) {
    const int cur = t & 1;
    if ((t & 15) == 0) {
#pragma unroll
      for (int i = 0; i < 2; ++i)
#pragma unroll
        for (int j = 0; j < 8; ++j) acc[i][j] = z;
    }
    if (t + 1 < 64) {
      stage(t + 1, cur ^ 1);
      asm volatile("s_waitcnt vmcnt(8)" ::: "memory");   // prev 8 done; 8 in flight
    } else {
      asm volatile("s_waitcnt vmcnt(0)" ::: "memory");
    }
    barrier_raw();

    const char* sb = smem + cur * 32768;
    const int a0o = kgrp * 2048 + (wrow0 + lane15) * 16;
    bf16x8 ah0 = *(const bf16x8*)(sb + a0o);
    bf16x8 ah1 = *(const bf16x8*)(sb + a0o + 256);
    bf16x8 al0 = *(const bf16x8*)(sb + 8192 + a0o);
    bf16x8 al1 = *(const bf16x8*)(sb + 8192 + a0o + 256);
#pragma unroll
    for (int cs = 0; cs < 8; ++cs) {
      const int bo = kgrp * 2048 + (cs * 16 + lane15) * 16;
      bf16x8 bh = *(const bf16x8*)(sb + 16384 + bo);
      bf16x8 bl = *(const bf16x8*)(sb + 24576 + bo);
      acc[0][cs] = __builtin_amdgcn_mfma_f32_16x16x32_bf16(ah0, bh, acc[0][cs], 0, 0, 0);
      acc[0][cs] = __builtin_amdgcn_mfma_f32_16x16x32_bf16(ah0, bl, acc[0][cs], 0, 0, 0);
      acc[0][cs] = __builtin_amdgcn_mfma_f32_16x16x32_bf16(al0, bh, acc[0][cs], 0, 0, 0);
      acc[1][cs] = __builtin_amdgcn_mfma_f32_16x16x32_bf16(ah1, bh, acc[1][cs], 0, 0, 0);
      acc[1][cs] = __builtin_amdgcn_mfma_f32_16x16x32_bf16(ah1, bl, acc[1][cs], 0, 0, 0);
      acc[1][cs] = __builtin_amdgcn_mfma_f32_16x16x32_bf16(al1, bh, acc[1][cs], 0, 0, 0);
    }
    barrier_raw();

    if ((t & 15) == 15) {                    // tile done -> chunked scan
      const int ct = t >> 4;
      const int ctile0 = slice * 512 + ct * 128;
#pragma unroll
      for (int ch = 0; ch < 4; ++ch) {
#pragma unroll
        for (int rs = 0; rs < 2; ++rs)
#pragma unroll
          for (int p = 0; p < 2; ++p) {
            const int cs = ch * 2 + p;
#pragma unroll
            for (int e = 0; e < 4; ++e) {
              const int row = wrow0 + rs * 16 + kgrp * 4 + e;
              const int col = p * 16 + lane15;
              Ssh[row * 32 + (col ^ ((row & 7) << 2))] = acc[rs][cs][e];
            }
          }
        barrier_lds();
        const int cbase = ctile0 + ch * 32 + shalf * 16;
        const int sw = (srow & 7) << 2;
#pragma unroll
        for (int c = 0; c < 16; ++c) {
          const float raw = Ssh[srow * 32 + ((shalf * 16 + c) ^ sw)];
          const float v = (raw + 1.0f) * 0.5f;
          const int gcol = cbase + c;
          if (gcol != rowg && v > t8v[7]) ins8(t8v, t8i, v, gcol);
        }
        barrier_raw();
      }
    }
  }

  float* Mv = Ssh;
  int*   Mi = (int*)(smem + 65536 + 4096);
  if (shalf) {
#pragma unroll
    for (int q = 0; q < 8; ++q) { Mv[srow * 8 + q] = t8v[q]; Mi[srow * 8 + q] = t8i[q]; }
  }
  barrier_lds();
  if (!shalf) {
#pragma unroll
    for (int q = 0; q < 8; ++q) {
      const float v = Mv[srow * 8 + q];
      if (v > t8v[7]) ins8(t8v, t8i, v, Mi[srow * 8 + q]);
    }
    const int prow = bN + rowg;
#pragma unroll
    for (int q = 0; q < 8; ++q) {
      pv[(prow * NSLICE + slice) * 8 + q] = t8v[q];
      pi[(prow * NSLICE + slice) * 8 + q] = bN + t8i[q];
    }
  }
}

// ----------------------------------------------------- merge slice partials
__global__ __launch_bounds__(256) void merge_topk(const float* __restrict__ pv,
                                                  const int* __restrict__ pi,
                                                  float* __restrict__ topv,
                                                  int* __restrict__ topi) {
  const int row = blockIdx.x * 256 + threadIdx.x;
  if (row >= BN) return;
  float tv[8]; int ti[8];
#pragma unroll
  for (int q = 0; q < 8; ++q) { tv[q] = -1.0f; ti[q] = 0; }
  for (int s = 0; s < NSLICE; ++s)
#pragma unroll
    for (int q = 0; q < 8; ++q) {
      const float v = pv[(row * NSLICE + s) * 8 + q];
      if (v > tv[7]) ins8(tv, ti, v, pi[(row * NSLICE + s) * 8 + q]);
    }
#pragma unroll
  for (int q = 0; q < 8; ++q) { topv[row * 8 + q] = tv[q]; topi[row * 8 + q] = ti[q]; }
}

// ------------------------------------------------------------- build edges
__global__ __launch_bounds__(256) void build_edges_kernel(const float* __restrict__ topv,
                                                          const int* __restrict__ topi,
                                                          int* __restrict__ ecnt,
                                                          int* __restrict__ eidx,
                                                          float* __restrict__ ew) {
  const int r = blockIdx.x * 256 + threadIdx.x;
  if (r >= BN) return;
#pragma unroll
  for (int t = 0; t < KTOP; ++t) {
    const float v = topv[r * KTOP + t];
    if (v > 0.0f) {
      const int j = topi[r * KTOP + t];
      const float w = 0.5f * v;
      int p = atomicAdd(&ecnt[r], 1);
      if (p < CAP) { eidx[r * CAP + p] = j; ew[r * CAP + p] = w; }
      int q = atomicAdd(&ecnt[j], 1);
      if (q < CAP) { eidx[j * CAP + q] = r; ew[j * CAP + q] = w; }
    }
  }
}

// ------------------------------------------------------------------ degree
__global__ __launch_bounds__(256) void deg_kernel(const int* __restrict__ ecnt,
                                                  const float* __restrict__ ew,
                                                  float* __restrict__ dis) {
  const int r = blockIdx.x * 256 + threadIdx.x;
  if (r >= BN) return;
  const int cnt = min(ecnt[r], CAP);
  float d = 1.0f;
  for (int e = 0; e < cnt; ++e) d += ew[r * CAP + e];
  dis[r] = rsqrtf(fmaxf(d, 1e-8f));
}

// ----------------------------------------------- y = x @ W via bf16 MFMA
// A from Xk [k8][BN][8], B from Wk [k8][512][8] -> coalesced staging.
__global__ __launch_bounds__(256, 2) void gemm_mfma(const __bf16* __restrict__ Xk,
                                                    const __bf16* __restrict__ Wk,
                                                    float* __restrict__ Y) {
  __shared__ __align__(16) char smem[32768];
  const int tid    = threadIdx.x;
  const int lane   = tid & 63;
  const int lane15 = tid & 15;
  const int kgrp   = (tid >> 4) & 3;
  const int wv     = tid >> 6;
  const int m0 = blockIdx.x * 128, n0 = blockIdx.y * 128;

  auto stage = [&](int t, int buf) {
    const int k80 = t << 2;
#pragma unroll
    for (int i = 0; i < 4; ++i) {
      const int c = (wv << 2) + i;           // 0..15: 0-7 X, 8-15 W
      const int kg = (c & 7) >> 1, rb = (c & 1) << 6;
      const __bf16* g = (c >> 3)
          ? Wk + ((size_t)(k80 + kg) * Dd + n0 + rb + lane) * 8
          : Xk + ((size_t)(k80 + kg) * BN + m0 + rb + lane) * 8;
      gload16(g, smem + buf * 16384 + ((c >> 3) << 13) + kg * 2048 + rb * 16);
    }
  };

  f32x4 acc[2][8];
  const f32x4 z = {0.f, 0.f, 0.f, 0.f};
#pragma unroll
  for (int i = 0; i < 2; ++i)
#pragma unroll
    for (int j = 0; j < 8; ++j) acc[i][j] = z;

  stage(0, 0);
  for (int t = 0; t < 16; ++t) {
    const int cur = t & 1;
    if (t + 1 < 16) {
      stage(t + 1, cur ^ 1);
      asm volatile("s_waitcnt vmcnt(4)" ::: "memory");
    } else {
      asm volatile("s_waitcnt vmcnt(0)" ::: "memory");
    }
    barrier_raw();

    const char* sb = smem + cur * 16384;
    const int a0o = kgrp * 2048 + (wv * 32 + lane15) * 16;
    bf16x8 a0 = *(const bf16x8*)(sb + a0o);
    bf16x8 a1 = *(const bf16x8*)(sb + a0o + 256);
#pragma unroll
    for (int cs = 0; cs < 8; ++cs) {
      bf16x8 b = *(const bf16x8*)(sb + 8192 + kgrp * 2048 + (cs * 16 + lane15) * 16);
      acc[0][cs] = __builtin_amdgcn_mfma_f32_16x16x32_bf16(a0, b, acc[0][cs], 0, 0, 0);
      acc[1][cs] = __builtin_amdgcn_mfma_f32_16x16x32_bf16(a1, b, acc[1][cs], 0, 0, 0);
    }
    barrier_raw();
  }
  const int rgrp = lane >> 4;
#pragma unroll
  for (int rs = 0; rs < 2; ++rs)
#pragma unroll
    for (int cs = 0; cs < 8; ++cs)
#pragma unroll
      for (int e = 0; e < 4; ++e) {
        const int row = m0 + wv * 32 + rs * 16 + rgrp * 4 + e;
        const int col = n0 + cs * 16 + lane15;
        Y[(size_t)row * Dd + col] = acc[rs][cs][e];
      }
}

// -------------------------------------------------- aggregation + LN (+LN)
__device__ inline void breduce2(float& s, float& q, float* red) {
#pragma unroll
  for (int o = 32; o; o >>= 1) { s += __shfl_down(s, o); q += __shfl_down(q, o); }
  const int wid = threadIdx.x >> 6, lane = threadIdx.x & 63;
  if (lane == 0) { red[wid * 2] = s; red[wid * 2 + 1] = q; }
  __syncthreads();
  if (threadIdx.x == 0) {
    float S = 0.f, Q = 0.f;
#pragma unroll
    for (int w2 = 0; w2 < 4; ++w2) { S += red[w2 * 2]; Q += red[w2 * 2 + 1]; }
    red[8] = S; red[9] = Q;
  }
  __syncthreads();
  s = red[8]; q = red[9];
}

// !FINAL: residual fp32 feats; writes h1 in k-major [k8][BN][8] (gemm2 input)
//  FINAL: residual bf16 h1k (k-major read); writes final fp32 out
template <bool FINAL>
__global__ __launch_bounds__(256) void agg_ln_kernel(const float* __restrict__ y,
                                                     const float* __restrict__ xres_f,
                                                     const __bf16* __restrict__ xres_k,
                                                     const int* __restrict__ ecnt,
                                                     const int* __restrict__ eidx,
                                                     const float* __restrict__ ew,
                                                     const float* __restrict__ dis,
                                                     const float* __restrict__ g1,
                                                     const float* __restrict__ b1v,
                                                     const float* __restrict__ g2,
                                                     const float* __restrict__ b2v,
                                                     float* __restrict__ outf,
                                                     __bf16* __restrict__ outk) {
  __shared__ float red[10];
  const int row = (blockIdx.x & 7) * Nn + (blockIdx.x >> 3);  // batch->XCD affinity
  const int tid = threadIdx.x;
  const int d0 = tid * 2;
  const float di = dis[row];

  float2 yv = *(const float2*)(y + (size_t)row * Dd + d0);
  float a0 = di * di * yv.x, a1 = di * di * yv.y;
  const int cnt = min(ecnt[row], CAP);
  for (int e = 0; e < cnt; ++e) {
    const int j = eidx[row * CAP + e];
    const float c = ew[row * CAP + e] * di * dis[j];
    float2 v = *(const float2*)(y + (size_t)j * Dd + d0);
    a0 += c * v.x; a1 += c * v.y;
  }
  if (FINAL) {
    bf16x2 u = *(const bf16x2*)(xres_k + ((size_t)(tid >> 2) * BN + row) * 8 + (tid & 3) * 2);
    a0 += (float)u[0]; a1 += (float)u[1];
  } else {
    float2 xv = *(const float2*)(xres_f + (size_t)row * Dd + d0);
    a0 += xv.x; a1 += xv.y;
  }

  float s = a0 + a1, q = a0 * a0 + a1 * a1;
  breduce2(s, q, red);
  const float mu = s * (1.0f / Dd);
  const float var = q * (1.0f / Dd) - mu * mu;
  const float rs = rsqrtf(var + 1e-5f);
  float t0 = fmaxf((a0 - mu) * rs * g1[d0]     + b1v[d0],     0.0f);
  float t1 = fmaxf((a1 - mu) * rs * g1[d0 + 1] + b1v[d0 + 1], 0.0f);

  if (FINAL) {
    float s2 = t0 + t1, q2 = t0 * t0 + t1 * t1;
    breduce2(s2, q2, red);
    const float mu2 = s2 * (1.0f / Dd);
    const float var2 = q2 * (1.0f / Dd) - mu2 * mu2;
    const float rs2 = rsqrtf(var2 + 1e-5f);
    const float o0 = (t0 - mu2) * rs2 * g2[d0]     + b2v[d0];
    const float o1 = (t1 - mu2) * rs2 * g2[d0 + 1] + b2v[d0 + 1];
    *(float2*)(outf + (size_t)row * Dd + d0) = make_float2(o0, o1);
  } else {
    bf16x2 ov; ov[0] = (__bf16)t0; ov[1] = (__bf16)t1;
    *(bf16x2*)(outk + ((size_t)(tid >> 2) * BN + row) * 8 + (tid & 3) * 2) = ov;
  }
}

// ------------------------------------------------------------------ launch
extern "C" void kernel_launch(void* const* d_in, const int* in_sizes, int n_in,
                              void* d_out, int out_size, void* d_ws, size_t ws_size,
                              hipStream_t stream) {
  const float* feats = (const float*)d_in[0];
  const float* W1    = (const float*)d_in[2];
  const float* ln1_g = (const float*)d_in[3];
  const float* ln1_b = (const float*)d_in[4];
  const float* W2    = (const float*)d_in[5];
  const float* ln2_g = (const float*)d_in[6];
  const float* ln2_b = (const float*)d_in[7];
  const float* out_g = (const float*)d_in[8];
  const float* out_b = (const float*)d_in[9];
  float* out = (float*)d_out;

  char* w = (char*)d_ws;
  float* rinv = (float*)w; w += (size_t)BN * 4;
  float* topv = (float*)w; w += (size_t)BN * KTOP * 4;
  int*   topi = (int*)w;   w += (size_t)BN * KTOP * 4;
  int*   ecnt = (int*)w;   w += (size_t)BN * 4;
  int*   eidx = (int*)w;   w += (size_t)BN * CAP * 4;
  float* ew   = (float*)w; w += (size_t)BN * CAP * 4;
  float* dis  = (float*)w; w += (size_t)BN * 4;
  __bf16* Wk1 = (__bf16*)w; w += (size_t)Dd * Dd * 2;
  __bf16* Wk2 = (__bf16*)w; w += (size_t)Dd * Dd * 2;
  float* ybuf = (float*)w; w += (size_t)BN * Dd * 4;   // 32 MB
  __bf16* Xk  = (__bf16*)w; w += (size_t)BN * Dd * 2;  // 16 MB (k-major)
  __bf16* h1k = (__bf16*)w; w += (size_t)BN * Dd * 2;  // 16 MB (k-major)
  __bf16* Hk = (__bf16*)ybuf;                          // overlay (dead before gemm1)
  __bf16* Lk = Hk + (size_t)BN * Dd;
  float* pv  = (float*)h1k;                            // overlay (dead before agg1)
  int*   pi  = (int*)((char*)h1k + (size_t)BN * NSLICE * 8 * 4);

  hipMemsetAsync(ecnt, 0, (size_t)BN * 4, stream);

  rownorm_kernel<<<BN / 4, 256, 0, stream>>>(feats, rinv);
  split_kernel<<<BN / 64, 256, 0, stream>>>(feats, rinv, Hk, Lk, Xk);
  wcast_t<<<dim3(16, 16), 256, 0, stream>>>(W1, Wk1);
  wcast_t<<<dim3(16, 16), 256, 0, stream>>>(W2, Wk2);

  sim_mfma_topk<<<512, 256, 0, stream>>>(Hk, Lk, pv, pi);
  merge_topk<<<BN / 256, 256, 0, stream>>>(pv, pi, topv, topi);
  build_edges_kernel<<<BN / 256, 256, 0, stream>>>(topv, topi, ecnt, eidx, ew);
  deg_kernel<<<BN / 256, 256, 0, stream>>>(ecnt, ew, dis);

  gemm_mfma<<<dim3(BN / 128, Dd / 128), 256, 0, stream>>>(Xk, Wk1, ybuf);
  agg_ln_kernel<false><<<BN, 256, 0, stream>>>(ybuf, feats, nullptr, ecnt, eidx, ew, dis,
                                               ln1_g, ln1_b, nullptr, nullptr,
                                               nullptr, h1k);
  gemm_mfma<<<dim3(BN / 128, Dd / 128), 256, 0, stream>>>(h1k, Wk2, ybuf);
  agg_ln_kernel<true><<<BN, 256, 0, stream>>>(ybuf, nullptr, h1k, ecnt, eidx, ew, dis,
                                              ln2_g, ln2_b, out_g, out_b,
                                              out, nullptr);
}

// Round 7
// 315.209 us; speedup vs baseline: 1.8230x; 1.2277x over previous
//
#include <hip/hip_runtime.h>
#include <cstdint>

// ---------------------------------------------------------------------------
// SimilarityGCNEncoder: B=8, N=2048, D=512, fp32.
// r7: swapped-operand MFMA (mfma(B,A)) in sim & gemm -> each lane owns a row's
// cols in registers: sim's top-8 runs fully in-register (no LDS scan, -32
// barriers, -512 ds-ops/thread) with a 2-step shfl_xor merge; gemm's C-write
// becomes bf16x4 stores and y is bf16 (halves gemm-write + agg-read bytes).
// agg: 128 thr/block, 4 elems/thread. merge+edges fused.
// Layouts (unchanged from r6): Hk/Lk [b][k8][n][8], Xk/h1k [k8][BN][8],
// Wk [k8][n][8]; k-major so global_load_lds staging is fully coalesced.
// ---------------------------------------------------------------------------

constexpr int Bb   = 8;
constexpr int Nn   = 2048;
constexpr int Dd   = 512;
constexpr int BN   = Bb * Nn;
constexpr int KTOP = 8;
constexpr int CAP  = 56;
constexpr int NSLICE = 4;

typedef __attribute__((ext_vector_type(8))) __bf16 bf16x8;
typedef __attribute__((ext_vector_type(4))) __bf16 bf16x4;
typedef __attribute__((ext_vector_type(4))) float  f32x4;

__device__ __forceinline__ void gload16(const void* g, void* l) {
  __builtin_amdgcn_global_load_lds((const __attribute__((address_space(1))) unsigned int*)g,
                                   (__attribute__((address_space(3))) unsigned int*)l,
                                   16, 0, 0);
}
__device__ __forceinline__ void barrier_raw() {
  asm volatile("" ::: "memory");
  __builtin_amdgcn_s_barrier();
  asm volatile("" ::: "memory");
}

// ---------------------------------------------------------------- row norms
__global__ __launch_bounds__(256) void rownorm_kernel(const float* __restrict__ feats,
                                                      float* __restrict__ rinv) {
  const int row  = blockIdx.x * 4 + (threadIdx.x >> 6);
  const int lane = threadIdx.x & 63;
  const float* p = feats + (size_t)row * Dd + lane * 8;
  float4 a = *(const float4*)p;
  float4 b = *(const float4*)(p + 4);
  float s = a.x*a.x + a.y*a.y + a.z*a.z + a.w*a.w
          + b.x*b.x + b.y*b.y + b.z*b.z + b.w*b.w;
#pragma unroll
  for (int o = 32; o; o >>= 1) s += __shfl_down(s, o);
  if (lane == 0) rinv[row] = 1.0f / fmaxf(sqrtf(s), 1e-8f);
}

// --------------------------- split + cast, k-major outputs (LDS transpose)
__global__ __launch_bounds__(256) void split_kernel(const float* __restrict__ feats,
                                                    const float* __restrict__ rinv,
                                                    __bf16* __restrict__ Hk,
                                                    __bf16* __restrict__ Lk,
                                                    __bf16* __restrict__ Xk) {
  __shared__ float tile[64][65];
  __shared__ float rsh[64];
  const int r0 = blockIdx.x * 64;
  const int bz = r0 >> 11;
  const int n0 = r0 & 2047;
  const int t  = threadIdx.x;
  if (t < 64) rsh[t] = rinv[r0 + t];

  for (int kt = 0; kt < 8; ++kt) {
    __syncthreads();
#pragma unroll
    for (int p = 0; p < 4; ++p) {
      const int row = p * 16 + (t >> 4), ch = t & 15;
      float4 v = *(const float4*)(feats + (size_t)(r0 + row) * Dd + kt * 64 + ch * 4);
      tile[row][ch * 4 + 0] = v.x; tile[row][ch * 4 + 1] = v.y;
      tile[row][ch * 4 + 2] = v.z; tile[row][ch * 4 + 3] = v.w;
    }
    __syncthreads();
#pragma unroll
    for (int h = 0; h < 2; ++h) {
      const int c = h * 256 + t;
      const int k8l = c >> 6, row = c & 63;
      const float s = rsh[row];
      bf16x8 hv, lv, xv;
#pragma unroll
      for (int e = 0; e < 8; ++e) {
        const float x = tile[row][k8l * 8 + e];
        xv[e] = (__bf16)x;
        const float nm = x * s;
        const __bf16 hh = (__bf16)nm;
        hv[e] = hh;
        lv[e] = (__bf16)(nm - (float)hh);
      }
      const size_t kk = (size_t)(kt * 8 + k8l);
      *(bf16x8*)(Hk + ((size_t)(bz * 64) + kk) * (Nn * 8) + (n0 + row) * 8) = hv;
      *(bf16x8*)(Lk + ((size_t)(bz * 64) + kk) * (Nn * 8) + (n0 + row) * 8) = lv;
      *(bf16x8*)(Xk + kk * ((size_t)BN * 8) + (size_t)(r0 + row) * 8) = xv;
    }
  }
}

// --------------------------------- W cast -> k-major Wk[k8][n=512][8] bf16
__global__ __launch_bounds__(256) void wcast_t(const float* __restrict__ W,
                                               __bf16* __restrict__ Wk) {
  __shared__ float t[32][33];
  const int bx = blockIdx.x * 32, by = blockIdx.y * 32;   // bx=n, by=k
  const int lx = threadIdx.x & 31, ly = threadIdx.x >> 5;
#pragma unroll
  for (int r = 0; r < 32; r += 8)
    t[ly + r][lx] = W[(size_t)(by + ly + r) * Dd + bx + lx];
  __syncthreads();
  if (threadIdx.x < 128) {
    const int k8l = threadIdx.x >> 5, nl = threadIdx.x & 31;
    bf16x8 v;
#pragma unroll
    for (int e = 0; e < 8; ++e) v[e] = (__bf16)t[k8l * 8 + e][nl];
    *(bf16x8*)(Wk + ((size_t)((by >> 3) + k8l) * Dd + bx + nl) * 8) = v;
  }
}

// ---------------------------------------------------- top-8 insert helpers
__device__ __forceinline__ void ins8(float (&tv)[8], int (&ti)[8], float v, int idx) {
#pragma unroll
  for (int q = 0; q < 8; ++q) {
    bool sw = v > tv[q];
    float a = sw ? tv[q] : v;
    int   c = sw ? ti[q] : idx;
    tv[q] = sw ? v   : tv[q];
    ti[q] = sw ? idx : ti[q];
    v = a; idx = c;
  }
}
// with lower-index tie-break (cross-lane merge: col order not monotone)
__device__ __forceinline__ void ins8t(float (&tv)[8], int (&ti)[8], float v, int idx) {
#pragma unroll
  for (int q = 0; q < 8; ++q) {
    bool sw = (v > tv[q]) || (v == tv[q] && idx < ti[q]);
    float a = sw ? tv[q] : v;
    int   c = sw ? ti[q] : idx;
    tv[q] = sw ? v   : tv[q];
    ti[q] = sw ? idx : ti[q];
    v = a; idx = c;
  }
}

// ------------------------------------------- split-bf16 MFMA sim + top-8
// Swapped operands: mfma(Bfrag, Afrag) -> lane&15 = row, (lane>>4)*4+e = col.
// Each lane owns 2 rows x 32 cols in registers; top-8 fully in-register.
__global__ __launch_bounds__(256, 2) void sim_mfma_topk(const __bf16* __restrict__ Hk,
                                                        const __bf16* __restrict__ Lk,
                                                        float* __restrict__ pv,
                                                        int* __restrict__ pi) {
  __shared__ __align__(16) char smem[65536];   // dbuf staging only

  const int f     = blockIdx.x;
  const int bz    = f & 7;                  // batch == XCD id
  const int rr    = f >> 3;
  const int r0    = (rr & 15) * 128;
  const int slice = rr >> 4;

  const int tid    = threadIdx.x;
  const int lane   = tid & 63;
  const int lane15 = tid & 15;
  const int kgrp   = (tid >> 4) & 3;        // == lane>>4 within wave
  const int wv     = tid >> 6;
  const int wrow0  = wv * 32;
  const int bN     = bz * Nn;

  const __bf16* Hb = Hk + (size_t)(bz * 64) * (Nn * 8);
  const __bf16* Lb = Lk + (size_t)(bz * 64) * (Nn * 8);

  float t8v[2][8]; int t8i[2][8];
#pragma unroll
  for (int rs = 0; rs < 2; ++rs)
#pragma unroll
    for (int q = 0; q < 8; ++q) { t8v[rs][q] = -1.0f; t8i[rs][q] = 0; }

  // wave wv stages one region per step: 0=AH 1=AL 2=BH 3=BL
  auto stage = [&](int t, int buf) {
    const int ct = t >> 4, k80 = (t & 15) << 2;
    const int rbase = (wv < 2) ? r0 : slice * 512 + ct * 128;
    const __bf16* base = ((wv & 1) == 0) ? Hb : Lb;
    char* ldsb = smem + buf * 32768 + wv * 8192;
#pragma unroll
    for (int i = 0; i < 8; ++i) {
      const int kg = i >> 1, rb = (i & 1) << 6;
      gload16(base + ((size_t)(k80 + kg) * Nn + rbase + rb + lane) * 8,
              ldsb + kg * 2048 + rb * 16);
    }
  };

  f32x4 acc[2][8];
  const f32x4 z = {0.f, 0.f, 0.f, 0.f};

  stage(0, 0);
  for (int t = 0; t < 64; ++t) {
    const int cur = t & 1;
    if ((t & 15) == 0) {
#pragma unroll
      for (int i = 0; i < 2; ++i)
#pragma unroll
        for (int j = 0; j < 8; ++j) acc[i][j] = z;
    }
    if (t + 1 < 64) {
      stage(t + 1, cur ^ 1);
      asm volatile("s_waitcnt vmcnt(8)" ::: "memory");
    } else {
      asm volatile("s_waitcnt vmcnt(0)" ::: "memory");
    }
    barrier_raw();

    const char* sb = smem + cur * 32768;
    const int a0o = kgrp * 2048 + (wrow0 + lane15) * 16;
    bf16x8 ah0 = *(const bf16x8*)(sb + a0o);
    bf16x8 ah1 = *(const bf16x8*)(sb + a0o + 256);
    bf16x8 al0 = *(const bf16x8*)(sb + 8192 + a0o);
    bf16x8 al1 = *(const bf16x8*)(sb + 8192 + a0o + 256);
#pragma unroll
    for (int cs = 0; cs < 8; ++cs) {
      const int bo = kgrp * 2048 + (cs * 16 + lane15) * 16;
      bf16x8 bh = *(const bf16x8*)(sb + 16384 + bo);
      bf16x8 bl = *(const bf16x8*)(sb + 24576 + bo);
      // swapped: C[col][row]; terms HH + LbHa + HbLa
      acc[0][cs] = __builtin_amdgcn_mfma_f32_16x16x32_bf16(bh, ah0, acc[0][cs], 0, 0, 0);
      acc[0][cs] = __builtin_amdgcn_mfma_f32_16x16x32_bf16(bl, ah0, acc[0][cs], 0, 0, 0);
      acc[0][cs] = __builtin_amdgcn_mfma_f32_16x16x32_bf16(bh, al0, acc[0][cs], 0, 0, 0);
      acc[1][cs] = __builtin_amdgcn_mfma_f32_16x16x32_bf16(bh, ah1, acc[1][cs], 0, 0, 0);
      acc[1][cs] = __builtin_amdgcn_mfma_f32_16x16x32_bf16(bl, ah1, acc[1][cs], 0, 0, 0);
      acc[1][cs] = __builtin_amdgcn_mfma_f32_16x16x32_bf16(bh, al1, acc[1][cs], 0, 0, 0);
    }
    barrier_raw();

    if ((t & 15) == 15) {                    // tile done -> in-register scan
      const int ct = t >> 4;
      const int ctile0 = slice * 512 + ct * 128;
#pragma unroll
      for (int rs = 0; rs < 2; ++rs) {
        const int rowg = r0 + wrow0 + rs * 16 + lane15;   // batch-local row
#pragma unroll
        for (int cs = 0; cs < 8; ++cs)
#pragma unroll
          for (int e = 0; e < 4; ++e) {
            const int col = ctile0 + cs * 16 + kgrp * 4 + e;
            const float v = (acc[rs][cs][e] + 1.0f) * 0.5f;
            if (col != rowg && v > t8v[rs][7]) ins8(t8v[rs], t8i[rs], v, col);
          }
      }
    }
  }

  // merge the 4 col-quarters per row across lanes {L, L^16, L^32, L^48}
#pragma unroll
  for (int rs = 0; rs < 2; ++rs) {
#pragma unroll
    for (int m = 16; m <= 32; m <<= 1) {
      float ov[8]; int oi[8];
#pragma unroll
      for (int q = 0; q < 8; ++q) {          // snapshot partner BEFORE inserting
        ov[q] = __shfl_xor(t8v[rs][q], m);
        oi[q] = __shfl_xor(t8i[rs][q], m);
      }
#pragma unroll
      for (int q = 0; q < 8; ++q)
        if (ov[q] > t8v[rs][7] || (ov[q] == t8v[rs][7] && oi[q] < t8i[rs][7]))
          ins8t(t8v[rs], t8i[rs], ov[q], oi[q]);
    }
  }

  if (lane < 16) {
#pragma unroll
    for (int rs = 0; rs < 2; ++rs) {
      const int prow = bN + r0 + wrow0 + rs * 16 + lane15;
#pragma unroll
      for (int q = 0; q < 8; ++q) {
        pv[(prow * NSLICE + slice) * 8 + q] = t8v[rs][q];
        pi[(prow * NSLICE + slice) * 8 + q] = bN + t8i[rs][q];
      }
    }
  }
}

// -------------------------------- merge slice partials + build edges (fused)
__global__ __launch_bounds__(256) void merge_edges(const float* __restrict__ pv,
                                                   const int* __restrict__ pi,
                                                   int* __restrict__ ecnt,
                                                   int* __restrict__ eidx,
                                                   float* __restrict__ ew) {
  const int row = blockIdx.x * 256 + threadIdx.x;
  if (row >= BN) return;
  float tv[8]; int ti[8];
#pragma unroll
  for (int q = 0; q < 8; ++q) { tv[q] = -1.0f; ti[q] = 0; }
  for (int s = 0; s < NSLICE; ++s)          // slices = ascending disjoint col
#pragma unroll
    for (int q = 0; q < 8; ++q) {
      const float v = pv[(row * NSLICE + s) * 8 + q];
      if (v > tv[7]) ins8(tv, ti, v, pi[(row * NSLICE + s) * 8 + q]);
    }
#pragma unroll
  for (int t = 0; t < KTOP; ++t) {
    if (tv[t] > 0.0f) {
      const int j = ti[t];
      const float w = 0.5f * tv[t];
      int p = atomicAdd(&ecnt[row], 1);
      if (p < CAP) { eidx[row * CAP + p] = j; ew[row * CAP + p] = w; }
      int q2 = atomicAdd(&ecnt[j], 1);
      if (q2 < CAP) { eidx[j * CAP + q2] = row; ew[j * CAP + q2] = w; }
    }
  }
}

// ------------------------------------------------------------------ degree
__global__ __launch_bounds__(256) void deg_kernel(const int* __restrict__ ecnt,
                                                  const float* __restrict__ ew,
                                                  float* __restrict__ dis) {
  const int r = blockIdx.x * 256 + threadIdx.x;
  if (r >= BN) return;
  const int cnt = min(ecnt[r], CAP);
  float d = 1.0f;
  for (int e = 0; e < cnt; ++e) d += ew[r * CAP + e];
  dis[r] = rsqrtf(fmaxf(d, 1e-8f));
}

// ------------------------------- y = x @ W via bf16 MFMA, bf16 output
// Swapped operands -> lane owns row (lane&15) x col-quads -> bf16x4 stores.
__global__ __launch_bounds__(256, 2) void gemm_mfma(const __bf16* __restrict__ Xk,
                                                    const __bf16* __restrict__ Wk,
                                                    __bf16* __restrict__ Yb) {
  __shared__ __align__(16) char smem[32768];
  const int tid    = threadIdx.x;
  const int lane   = tid & 63;
  const int lane15 = tid & 15;
  const int kgrp   = (tid >> 4) & 3;
  const int wv     = tid >> 6;
  const int m0 = blockIdx.x * 128, n0 = blockIdx.y * 128;

  auto stage = [&](int t, int buf) {
    const int k80 = t << 2;
#pragma unroll
    for (int i = 0; i < 4; ++i) {
      const int c = (wv << 2) + i;
      const int kg = (c & 7) >> 1, rb = (c & 1) << 6;
      const __bf16* g = (c >> 3)
          ? Wk + ((size_t)(k80 + kg) * Dd + n0 + rb + lane) * 8
          : Xk + ((size_t)(k80 + kg) * BN + m0 + rb + lane) * 8;
      gload16(g, smem + buf * 16384 + ((c >> 3) << 13) + kg * 2048 + rb * 16);
    }
  };

  f32x4 acc[2][8];
  const f32x4 z = {0.f, 0.f, 0.f, 0.f};
#pragma unroll
  for (int i = 0; i < 2; ++i)
#pragma unroll
    for (int j = 0; j < 8; ++j) acc[i][j] = z;

  stage(0, 0);
  for (int t = 0; t < 16; ++t) {
    const int cur = t & 1;
    if (t + 1 < 16) {
      stage(t + 1, cur ^ 1);
      asm volatile("s_waitcnt vmcnt(4)" ::: "memory");
    } else {
      asm volatile("s_waitcnt vmcnt(0)" ::: "memory");
    }
    barrier_raw();

    const char* sb = smem + cur * 16384;
    const int a0o = kgrp * 2048 + (wv * 32 + lane15) * 16;
    bf16x8 a0 = *(const bf16x8*)(sb + a0o);
    bf16x8 a1 = *(const bf16x8*)(sb + a0o + 256);
#pragma unroll
    for (int cs = 0; cs < 8; ++cs) {
      bf16x8 b = *(const bf16x8*)(sb + 8192 + kgrp * 2048 + (cs * 16 + lane15) * 16);
      acc[0][cs] = __builtin_amdgcn_mfma_f32_16x16x32_bf16(b, a0, acc[0][cs], 0, 0, 0);
      acc[1][cs] = __builtin_amdgcn_mfma_f32_16x16x32_bf16(b, a1, acc[1][cs], 0, 0, 0);
    }
    barrier_raw();
  }
#pragma unroll
  for (int rs = 0; rs < 2; ++rs) {
    const int row = m0 + wv * 32 + rs * 16 + lane15;
#pragma unroll
    for (int cs = 0; cs < 8; ++cs) {
      bf16x4 o;
#pragma unroll
      for (int e = 0; e < 4; ++e) o[e] = (__bf16)acc[rs][cs][e];
      *(bf16x4*)(Yb + (size_t)row * Dd + n0 + cs * 16 + kgrp * 4) = o;
    }
  }
}

// -------------------------------------------------- aggregation + LN (+LN)
__device__ __forceinline__ void breduce2_128(float& s, float& q, float* red) {
#pragma unroll
  for (int o = 32; o; o >>= 1) { s += __shfl_down(s, o); q += __shfl_down(q, o); }
  __syncthreads();                          // prior reads of red complete
  if ((threadIdx.x & 63) == 0) {
    red[(threadIdx.x >> 6) * 2]     = s;
    red[(threadIdx.x >> 6) * 2 + 1] = q;
  }
  __syncthreads();
  s = red[0] + red[2];
  q = red[1] + red[3];
}

// !FINAL: residual fp32 feats; writes h1 k-major bf16. FINAL: residual h1k;
// layer LN+ReLU then out LN -> fp32 out. 128 thr/block, 4 elems/thread.
template <bool FINAL>
__global__ __launch_bounds__(128) void agg_ln_kernel(const __bf16* __restrict__ yb,
                                                     const float* __restrict__ xres_f,
                                                     const __bf16* __restrict__ xres_k,
                                                     const int* __restrict__ ecnt,
                                                     const int* __restrict__ eidx,
                                                     const float* __restrict__ ew,
                                                     const float* __restrict__ dis,
                                                     const float* __restrict__ g1,
                                                     const float* __restrict__ b1v,
                                                     const float* __restrict__ g2,
                                                     const float* __restrict__ b2v,
                                                     float* __restrict__ outf,
                                                     __bf16* __restrict__ outk) {
  __shared__ float red[4];
  const int row = (blockIdx.x & 7) * Nn + (blockIdx.x >> 3);  // batch->XCD
  const int tid = threadIdx.x;
  const int d0 = tid * 4;
  const float di = dis[row];

  bf16x4 yv = *(const bf16x4*)(yb + (size_t)row * Dd + d0);
  float a[4];
#pragma unroll
  for (int e2 = 0; e2 < 4; ++e2) a[e2] = di * di * (float)yv[e2];
  const int cnt = min(ecnt[row], CAP);
  for (int e = 0; e < cnt; ++e) {
    const int j = eidx[row * CAP + e];
    const float c = ew[row * CAP + e] * di * dis[j];
    bf16x4 v = *(const bf16x4*)(yb + (size_t)j * Dd + d0);
#pragma unroll
    for (int e2 = 0; e2 < 4; ++e2) a[e2] += c * (float)v[e2];
  }
  if (FINAL) {
    bf16x4 u = *(const bf16x4*)(xres_k + ((size_t)(tid >> 1) * BN + row) * 8 + (tid & 1) * 4);
#pragma unroll
    for (int e2 = 0; e2 < 4; ++e2) a[e2] += (float)u[e2];
  } else {
    float4 xv = *(const float4*)(xres_f + (size_t)row * Dd + d0);
    a[0] += xv.x; a[1] += xv.y; a[2] += xv.z; a[3] += xv.w;
  }

  float s = a[0] + a[1] + a[2] + a[3];
  float qq = a[0]*a[0] + a[1]*a[1] + a[2]*a[2] + a[3]*a[3];
  breduce2_128(s, qq, red);
  const float mu = s * (1.0f / Dd);
  const float var = qq * (1.0f / Dd) - mu * mu;
  const float rs = rsqrtf(var + 1e-5f);
  float4 g = *(const float4*)(g1 + d0);
  float4 bb = *(const float4*)(b1v + d0);
  float tv[4];
  tv[0] = fmaxf((a[0] - mu) * rs * g.x + bb.x, 0.0f);
  tv[1] = fmaxf((a[1] - mu) * rs * g.y + bb.y, 0.0f);
  tv[2] = fmaxf((a[2] - mu) * rs * g.z + bb.z, 0.0f);
  tv[3] = fmaxf((a[3] - mu) * rs * g.w + bb.w, 0.0f);

  if (FINAL) {
    float s2 = tv[0] + tv[1] + tv[2] + tv[3];
    float q2 = tv[0]*tv[0] + tv[1]*tv[1] + tv[2]*tv[2] + tv[3]*tv[3];
    breduce2_128(s2, q2, red);
    const float mu2 = s2 * (1.0f / Dd);
    const float var2 = q2 * (1.0f / Dd) - mu2 * mu2;
    const float rs2 = rsqrtf(var2 + 1e-5f);
    float4 g2v = *(const float4*)(g2 + d0);
    float4 b2 = *(const float4*)(b2v + d0);
    float4 o;
    o.x = (tv[0] - mu2) * rs2 * g2v.x + b2.x;
    o.y = (tv[1] - mu2) * rs2 * g2v.y + b2.y;
    o.z = (tv[2] - mu2) * rs2 * g2v.z + b2.z;
    o.w = (tv[3] - mu2) * rs2 * g2v.w + b2.w;
    *(float4*)(outf + (size_t)row * Dd + d0) = o;
  } else {
    bf16x4 ov;
#pragma unroll
    for (int e2 = 0; e2 < 4; ++e2) ov[e2] = (__bf16)tv[e2];
    *(bf16x4*)(outk + ((size_t)(tid >> 1) * BN + row) * 8 + (tid & 1) * 4) = ov;
  }
}

// ------------------------------------------------------------------ launch
extern "C" void kernel_launch(void* const* d_in, const int* in_sizes, int n_in,
                              void* d_out, int out_size, void* d_ws, size_t ws_size,
                              hipStream_t stream) {
  const float* feats = (const float*)d_in[0];
  const float* W1    = (const float*)d_in[2];
  const float* ln1_g = (const float*)d_in[3];
  const float* ln1_b = (const float*)d_in[4];
  const float* W2    = (const float*)d_in[5];
  const float* ln2_g = (const float*)d_in[6];
  const float* ln2_b = (const float*)d_in[7];
  const float* out_g = (const float*)d_in[8];
  const float* out_b = (const float*)d_in[9];
  float* out = (float*)d_out;

  char* w = (char*)d_ws;
  float* rinv = (float*)w; w += (size_t)BN * 4;
  float* topv = (float*)w; w += (size_t)BN * KTOP * 4;   // (unused slot kept)
  int*   topi = (int*)w;   w += (size_t)BN * KTOP * 4;
  int*   ecnt = (int*)w;   w += (size_t)BN * 4;
  int*   eidx = (int*)w;   w += (size_t)BN * CAP * 4;
  float* ew   = (float*)w; w += (size_t)BN * CAP * 4;
  float* dis  = (float*)w; w += (size_t)BN * 4;
  __bf16* Wk1 = (__bf16*)w; w += (size_t)Dd * Dd * 2;
  __bf16* Wk2 = (__bf16*)w; w += (size_t)Dd * Dd * 2;
  float* ybuf = (float*)w; w += (size_t)BN * Dd * 4;   // 32 MB region
  __bf16* Xk  = (__bf16*)w; w += (size_t)BN * Dd * 2;  // 16 MB (k-major)
  __bf16* h1k = (__bf16*)w; w += (size_t)BN * Dd * 2;  // 16 MB (k-major)
  __bf16* Hk = (__bf16*)ybuf;                          // overlay (dead before gemm1)
  __bf16* Lk = Hk + (size_t)BN * Dd;
  __bf16* Yb = (__bf16*)ybuf;                          // bf16 y (after sim)
  float* pv  = (float*)h1k;                            // overlay (dead before agg1)
  int*   pi  = (int*)((char*)h1k + (size_t)BN * NSLICE * 8 * 4);
  (void)topv; (void)topi;

  hipMemsetAsync(ecnt, 0, (size_t)BN * 4, stream);

  rownorm_kernel<<<BN / 4, 256, 0, stream>>>(feats, rinv);
  split_kernel<<<BN / 64, 256, 0, stream>>>(feats, rinv, Hk, Lk, Xk);
  wcast_t<<<dim3(16, 16), 256, 0, stream>>>(W1, Wk1);
  wcast_t<<<dim3(16, 16), 256, 0, stream>>>(W2, Wk2);

  sim_mfma_topk<<<512, 256, 0, stream>>>(Hk, Lk, pv, pi);
  merge_edges<<<BN / 256, 256, 0, stream>>>(pv, pi, ecnt, eidx, ew);
  deg_kernel<<<BN / 256, 256, 0, stream>>>(ecnt, ew, dis);

  gemm_mfma<<<dim3(BN / 128, Dd / 128), 256, 0, stream>>>(Xk, Wk1, Yb);
  agg_ln_kernel<false><<<BN, 128, 0, stream>>>(Yb, feats, nullptr, ecnt, eidx, ew, dis,
                                               ln1_g, ln1_b, nullptr, nullptr,
                                               nullptr, h1k);
  gemm_mfma<<<dim3(BN / 128, Dd / 128), 256, 0, stream>>>(h1k, Wk2, Yb);
  agg_ln_kernel<true><<<BN, 128, 0, stream>>>(Yb, nullptr, h1k, ecnt, eidx, ew, dis,
                                              ln2_g, ln2_b, out_g, out_b,
                                              out, nullptr);
}